// Round 2
// baseline (417.116 us; speedup 1.0000x reference)
//
#include <hip/hip_runtime.h>

// MultiHeadAttentionLayer: n=4096, dim=512, h=8, d=64, fp32 in/out.
// bf16 MFMA everywhere, with Dekker split (hi+lo bf16) on Q,K,V,W and on the
// QK^T product so softmax sees scores accurate to ~1e-2 absolute (scores have
// sigma~170 here; plain bf16's ~1.5 absolute error flipped argmaxes -> R0 fail).

typedef __attribute__((ext_vector_type(8))) short bf16x8;
typedef __attribute__((ext_vector_type(4))) float f32x4;
typedef unsigned short u16;

static __device__ __forceinline__ u16 f2bf(float f) {
  union { float f; unsigned u; } v; v.f = f;
  unsigned r = v.u + 0x7fffu + ((v.u >> 16) & 1u);
  return (u16)(r >> 16);
}
static __device__ __forceinline__ float bf2f(u16 h) {
  union { unsigned u; float f; } v; v.u = ((unsigned)h) << 16; return v.f;
}

// ---------------- prep kernels ----------------
__global__ __launch_bounds__(256) void split_cvt(const float* __restrict__ in,
                                                 u16* __restrict__ hi,
                                                 u16* __restrict__ lo, int n4) {
  int i = blockIdx.x * blockDim.x + threadIdx.x;
  if (i < n4) {
    float4 v = ((const float4*)in)[i];
    ushort4 h, l;
    h.x = f2bf(v.x); l.x = f2bf(v.x - bf2f(h.x));
    h.y = f2bf(v.y); l.y = f2bf(v.y - bf2f(h.y));
    h.z = f2bf(v.z); l.z = f2bf(v.z - bf2f(h.z));
    h.w = f2bf(v.w); l.w = f2bf(v.w - bf2f(h.w));
    ((ushort4*)hi)[i] = h;
    ((ushort4*)lo)[i] = l;
  }
}

// out[b][c][r] = split(in[b][r][c])
__global__ __launch_bounds__(256) void transpose_split_cvt(const float* __restrict__ in,
                                                           u16* __restrict__ hi,
                                                           u16* __restrict__ lo,
                                                           int R, int C, int total) {
  for (int i = blockIdx.x * blockDim.x + threadIdx.x; i < total;
       i += gridDim.x * blockDim.x) {
    int rc = R * C;
    int b = i / rc, rem = i - b * rc;
    int c = rem / R, r = rem - c * R;
    float x = in[b * rc + r * C + c];
    u16 h = f2bf(x);
    hi[i] = h;
    lo[i] = f2bf(x - bf2f(h));
  }
}

// plain transpose (Wo)
__global__ __launch_bounds__(256) void transpose_cvt(const float* __restrict__ in,
                                                     u16* __restrict__ out,
                                                     int R, int C, int total) {
  for (int i = blockIdx.x * blockDim.x + threadIdx.x; i < total;
       i += gridDim.x * blockDim.x) {
    int rc = R * C;
    int b = i / rc, rem = i - b * rc;
    int c = rem / R, r = rem - c * R;
    out[i] = f2bf(in[b * rc + r * C + c]);
  }
}

// ---------------- batched GEMM: C[MxN] = (Ah+Al)[MxK] * (Bh+Bl)[NxK]^T -------
// MODE 0: split bf16 out  [b][row][col]        (q,k projections)
// MODE 1: plain bf16 out  [b][col][row]        (v projection, transposed)
// MODE 2: f32 out         [row][col], batch=1  (final projection)
template <int MODE, bool SPLIT>
__global__ __launch_bounds__(256) void gemm_bt(const u16* __restrict__ Ah,
                                               const u16* __restrict__ Al,
                                               const u16* __restrict__ Bh,
                                               const u16* __restrict__ Bl,
                                               u16* __restrict__ outh,
                                               u16* __restrict__ outl,
                                               float* __restrict__ outf,
                                               int M, int K, int N, float scale) {
  int rb = blockIdx.x, cb = blockIdx.y, b = blockIdx.z;
  int wave = threadIdx.x >> 6, lane = threadIdx.x & 63;
  int lr = lane & 15, lg = lane >> 4;
  int row0 = rb * 64 + wave * 16;

  const u16* Ahr = Ah + (size_t)(row0 + lr) * K;
  const u16* Alr = SPLIT ? Al + (size_t)(row0 + lr) * K : nullptr;
  const u16* Bhb = Bh + (size_t)b * N * K + (size_t)(cb * 64) * K;
  const u16* Blb = SPLIT ? Bl + (size_t)b * N * K + (size_t)(cb * 64) * K : nullptr;

  f32x4 acc[4] = {};
  for (int k0 = 0; k0 < K; k0 += 32) {
    bf16x8 ah = *(const bf16x8*)(Ahr + k0 + lg * 8);
    bf16x8 al;
    if (SPLIT) al = *(const bf16x8*)(Alr + k0 + lg * 8);
#pragma unroll
    for (int ct = 0; ct < 4; ++ct) {
      size_t boff = (size_t)(ct * 16 + lr) * K + k0 + lg * 8;
      bf16x8 bh = *(const bf16x8*)(Bhb + boff);
      acc[ct] = __builtin_amdgcn_mfma_f32_16x16x32_bf16(ah, bh, acc[ct], 0, 0, 0);
      if (SPLIT) {
        acc[ct] = __builtin_amdgcn_mfma_f32_16x16x32_bf16(al, bh, acc[ct], 0, 0, 0);
        bf16x8 bl = *(const bf16x8*)(Blb + boff);
        acc[ct] = __builtin_amdgcn_mfma_f32_16x16x32_bf16(ah, bl, acc[ct], 0, 0, 0);
      }
    }
  }
#pragma unroll
  for (int ct = 0; ct < 4; ++ct)
#pragma unroll
    for (int r = 0; r < 4; ++r) {
      float v = acc[ct][r] * scale;
      int row = row0 + lg * 4 + r;
      int col = cb * 64 + ct * 16 + lr;
      if (MODE == 0) {
        size_t idx = ((size_t)b * M + row) * N + col;
        u16 h = f2bf(v);
        outh[idx] = h;
        outl[idx] = f2bf(v - bf2f(h));
      } else if (MODE == 1) {
        outh[((size_t)b * N + col) * M + row] = f2bf(v);
      } else {
        outf[(size_t)row * N + col] = v;
      }
    }
}

// ---------------- flash attention ----------------
// qh,ql,kh,kl: [8][4096][64] bf16 (q pre-scaled by 1/8); vT: [8][64][4096] bf16
// att: [4096][512] bf16 (head-concat layout)
__global__ __launch_bounds__(256) void attn_kernel(const u16* __restrict__ qhh,
                                                   const u16* __restrict__ qhl,
                                                   const u16* __restrict__ khh,
                                                   const u16* __restrict__ khl,
                                                   const u16* __restrict__ vT,
                                                   u16* __restrict__ att) {
  const int n = 4096, d = 64;
  int qb = blockIdx.x, h = blockIdx.y;
  int wave = threadIdx.x >> 6, lane = threadIdx.x & 63;
  int lr = lane & 15, lg = lane >> 4;
  int t = threadIdx.x;

  __shared__ u16 Kh_lds[64][72];    // [key][dim] hi
  __shared__ u16 Kl_lds[64][72];    // [key][dim] lo
  __shared__ u16 V_lds[64][72];     // [dim][key]
  __shared__ u16 P_lds[4][16][72];  // per-wave P tile [qrow][key]

  int qrow0 = qb * 64 + wave * 16;
  bf16x8 qfh[2], qfl[2];
#pragma unroll
  for (int ks = 0; ks < 2; ++ks) {
    size_t qoff = ((size_t)h * n + qrow0 + lr) * d + ks * 32 + lg * 8;
    qfh[ks] = *(const bf16x8*)(qhh + qoff);
    qfl[ks] = *(const bf16x8*)(qhl + qoff);
  }

  f32x4 accO[4] = {};
  float m[4], l[4];
#pragma unroll
  for (int r = 0; r < 4; ++r) { m[r] = -INFINITY; l[r] = 0.f; }

  int rr = t >> 3, cc = (t & 7) * 8;
  const u16* khsrc0 = khh + (size_t)h * n * d;
  const u16* klsrc0 = khl + (size_t)h * n * d;
  const u16* vsrc0 = vT + (size_t)h * d * n;

  for (int kv0 = 0; kv0 < n; kv0 += 64) {
    const u16* khs = khsrc0 + (size_t)kv0 * d;
    const u16* kls = klsrc0 + (size_t)kv0 * d;
    const u16* vs = vsrc0 + kv0;
    *(bf16x8*)&Kh_lds[rr][cc]      = *(const bf16x8*)(khs + (size_t)rr * d + cc);
    *(bf16x8*)&Kh_lds[rr + 32][cc] = *(const bf16x8*)(khs + (size_t)(rr + 32) * d + cc);
    *(bf16x8*)&Kl_lds[rr][cc]      = *(const bf16x8*)(kls + (size_t)rr * d + cc);
    *(bf16x8*)&Kl_lds[rr + 32][cc] = *(const bf16x8*)(kls + (size_t)(rr + 32) * d + cc);
    *(bf16x8*)&V_lds[rr][cc]       = *(const bf16x8*)(vs + (size_t)rr * n + cc);
    *(bf16x8*)&V_lds[rr + 32][cc]  = *(const bf16x8*)(vs + (size_t)(rr + 32) * n + cc);
    __syncthreads();

    // S = (q_hi+q_lo)(K_hi+K_lo)^T, dropping lo*lo
    f32x4 s[4] = {};
#pragma unroll
    for (int ct = 0; ct < 4; ++ct) {
#pragma unroll
      for (int ks = 0; ks < 2; ++ks) {
        bf16x8 bh = *(const bf16x8*)&Kh_lds[ct * 16 + lr][ks * 32 + lg * 8];
        s[ct] = __builtin_amdgcn_mfma_f32_16x16x32_bf16(qfh[ks], bh, s[ct], 0, 0, 0);
        s[ct] = __builtin_amdgcn_mfma_f32_16x16x32_bf16(qfl[ks], bh, s[ct], 0, 0, 0);
        bf16x8 bl = *(const bf16x8*)&Kl_lds[ct * 16 + lr][ks * 32 + lg * 8];
        s[ct] = __builtin_amdgcn_mfma_f32_16x16x32_bf16(qfh[ks], bl, s[ct], 0, 0, 0);
      }
    }

    // online softmax; lane owns rows lg*4+r at key col lr (+16*ct)
#pragma unroll
    for (int r = 0; r < 4; ++r) {
      float mx = fmaxf(fmaxf(s[0][r], s[1][r]), fmaxf(s[2][r], s[3][r]));
#pragma unroll
      for (int msk = 1; msk < 16; msk <<= 1) mx = fmaxf(mx, __shfl_xor(mx, msk));
      float mn = fmaxf(m[r], mx);
      float alpha = __expf(m[r] - mn);
      m[r] = mn;
      float rs = 0.f;
#pragma unroll
      for (int ct = 0; ct < 4; ++ct) {
        float p = __expf(s[ct][r] - mn);
        s[ct][r] = p;
        rs += p;
      }
#pragma unroll
      for (int msk = 1; msk < 16; msk <<= 1) rs += __shfl_xor(rs, msk);
      l[r] = l[r] * alpha + rs;
#pragma unroll
      for (int dt = 0; dt < 4; ++dt) accO[dt][r] *= alpha;
    }

    // P -> LDS (wave-private), repack into A-fragment layout
#pragma unroll
    for (int ct = 0; ct < 4; ++ct)
#pragma unroll
      for (int r = 0; r < 4; ++r)
        P_lds[wave][lg * 4 + r][ct * 16 + lr] = f2bf(s[ct][r]);

    bf16x8 pa[2];
    pa[0] = *(const bf16x8*)&P_lds[wave][lr][lg * 8];
    pa[1] = *(const bf16x8*)&P_lds[wave][lr][32 + lg * 8];

    // O += P @ V
#pragma unroll
    for (int dt = 0; dt < 4; ++dt) {
#pragma unroll
      for (int ks = 0; ks < 2; ++ks) {
        bf16x8 vf = *(const bf16x8*)&V_lds[dt * 16 + lr][ks * 32 + lg * 8];
        accO[dt] = __builtin_amdgcn_mfma_f32_16x16x32_bf16(pa[ks], vf, accO[dt], 0, 0, 0);
      }
    }
    __syncthreads();
  }

#pragma unroll
  for (int r = 0; r < 4; ++r) {
    float inv = 1.f / l[r];
    int row = qrow0 + lg * 4 + r;
#pragma unroll
    for (int dt = 0; dt < 4; ++dt)
      att[(size_t)row * 512 + h * 64 + dt * 16 + lr] = f2bf(accO[dt][r] * inv);
  }
}

// ---------------- launch ----------------
extern "C" void kernel_launch(void* const* d_in, const int* in_sizes, int n_in,
                              void* d_out, int out_size, void* d_ws, size_t ws_size,
                              hipStream_t stream) {
  const float* Q = (const float*)d_in[0];
  const float* K = (const float*)d_in[1];
  const float* V = (const float*)d_in[2];
  const float* Wq = (const float*)d_in[3];
  const float* Wk = (const float*)d_in[4];
  const float* Wv = (const float*)d_in[5];
  const float* Wo = (const float*)d_in[6];
  float* out = (float*)d_out;

  const int n = 4096, dim = 512, h = 8, d = 64;
  const size_t MB = 1 << 20;
  char* ws = (char*)d_ws;
  // 32 MB peak via reuse: A-region recycled per input tensor; att reuses it too.
  u16* Ah   = (u16*)(ws + 0 * MB);             // 4 MB (split-hi of current input)
  u16* Al   = (u16*)(ws + 4 * MB);             // 4 MB
  u16* WqTh = (u16*)(ws + 8 * MB);
  u16* WqTl = (u16*)(ws + 8 * MB + 512 * 1024);
  u16* WkTh = (u16*)(ws + 9 * MB);
  u16* WkTl = (u16*)(ws + 9 * MB + 512 * 1024);
  u16* WvTh = (u16*)(ws + 10 * MB);
  u16* WvTl = (u16*)(ws + 10 * MB + 512 * 1024);
  u16* WoT  = (u16*)(ws + 11 * MB);            // 512 KB
  u16* qhh  = (u16*)(ws + 12 * MB);            // 4 MB each
  u16* qhl  = (u16*)(ws + 16 * MB);
  u16* khh  = (u16*)(ws + 20 * MB);
  u16* khl  = (u16*)(ws + 24 * MB);
  u16* vTp  = (u16*)(ws + 28 * MB);
  u16* att  = Ah;  // reused after projections are done

  int wtot = h * dim * d;
  transpose_split_cvt<<<(wtot + 255) / 256, 256, 0, stream>>>(Wq, WqTh, WqTl, dim, d, wtot);
  transpose_split_cvt<<<(wtot + 255) / 256, 256, 0, stream>>>(Wk, WkTh, WkTl, dim, d, wtot);
  transpose_split_cvt<<<(wtot + 255) / 256, 256, 0, stream>>>(Wv, WvTh, WvTl, dim, d, wtot);
  int wo_tot = dim * dim;
  transpose_cvt<<<(wo_tot + 255) / 256, 256, 0, stream>>>(Wo, WoT, dim, dim, wo_tot);

  int n4 = n * dim / 4;
  dim3 gp(n / 64, 1, h);
  // q = (Q @ Wq) / 8, split-stored
  split_cvt<<<(n4 + 255) / 256, 256, 0, stream>>>(Q, Ah, Al, n4);
  gemm_bt<0, true><<<gp, 256, 0, stream>>>(Ah, Al, WqTh, WqTl, qhh, qhl, nullptr,
                                           n, dim, d, 0.125f);
  // k = K @ Wk, split-stored
  split_cvt<<<(n4 + 255) / 256, 256, 0, stream>>>(K, Ah, Al, n4);
  gemm_bt<0, true><<<gp, 256, 0, stream>>>(Ah, Al, WkTh, WkTl, khh, khl, nullptr,
                                           n, dim, d, 1.0f);
  // v = V @ Wv, plain bf16, stored transposed [h][d][n]
  split_cvt<<<(n4 + 255) / 256, 256, 0, stream>>>(V, Ah, Al, n4);
  gemm_bt<1, true><<<gp, 256, 0, stream>>>(Ah, Al, WvTh, WvTl, vTp, nullptr, nullptr,
                                           n, dim, d, 1.0f);

  attn_kernel<<<dim3(n / 64, h), 256, 0, stream>>>(qhh, qhl, khh, khl, vTp, att);

  gemm_bt<2, false><<<dim3(n / 64, dim / 64, 1), 256, 0, stream>>>(
      att, nullptr, WoT, nullptr, nullptr, nullptr, out, n, dim, dim, 1.0f);
}

// Round 3
// 321.412 us; speedup vs baseline: 1.2978x; 1.2978x over previous
//
#include <hip/hip_runtime.h>

// MultiHeadAttentionLayer: n=4096, dim=512, h=8, d=64, fp32 in/out.
// bf16 MFMA + Dekker split (hi+lo) on everything upstream of the softmax exp.
// R3: split-KV x2 (occupancy 25%->50%), XOR-swizzled LDS (bank conflicts),
//     in-register A-split in projection GEMMs (drops split_cvt kernels).

typedef __attribute__((ext_vector_type(8))) short bf16x8;
typedef __attribute__((ext_vector_type(4))) float f32x4;
typedef unsigned short u16;

static __device__ __forceinline__ u16 f2bf(float f) {
  union { float f; unsigned u; } v; v.f = f;
  unsigned r = v.u + 0x7fffu + ((v.u >> 16) & 1u);
  return (u16)(r >> 16);
}
static __device__ __forceinline__ float bf2f(u16 h) {
  union { unsigned u; float f; } v; v.u = ((unsigned)h) << 16; return v.f;
}

// element (row, col[u16]) of a [64|16]x64 u16 tile lives at byte
// (row*128 + col*2) ^ ((row&7)<<4)  -- spreads 8-row stripes over all banks.
#define SWZ(row, byteoff) ((((row) * 128) + (byteoff)) ^ (((row) & 7) << 4))

// ---------------- prep kernels (weights only) ----------------
__global__ __launch_bounds__(256) void transpose_split_cvt(const float* __restrict__ in,
                                                           u16* __restrict__ hi,
                                                           u16* __restrict__ lo,
                                                           int R, int C, int total) {
  for (int i = blockIdx.x * blockDim.x + threadIdx.x; i < total;
       i += gridDim.x * blockDim.x) {
    int rc = R * C;
    int b = i / rc, rem = i - b * rc;
    int c = rem / R, r = rem - c * R;
    float x = in[b * rc + r * C + c];
    u16 h = f2bf(x);
    hi[i] = h;
    lo[i] = f2bf(x - bf2f(h));
  }
}

__global__ __launch_bounds__(256) void transpose_cvt(const float* __restrict__ in,
                                                     u16* __restrict__ out,
                                                     int R, int C, int total) {
  for (int i = blockIdx.x * blockDim.x + threadIdx.x; i < total;
       i += gridDim.x * blockDim.x) {
    int rc = R * C;
    int b = i / rc, rem = i - b * rc;
    int c = rem / R, r = rem - c * R;
    out[i] = f2bf(in[b * rc + r * C + c]);
  }
}

// ------------- projection GEMM: C = (A_f32)[MxK] * (Bh+Bl)[NxK]^T -------------
// A loaded fp32 and Dekker-split in registers. MODE 0: split bf16 out [b][row][col]
// (q,k). MODE 1: plain bf16 out [b][col][row] (v, transposed).
template <int MODE>
__global__ __launch_bounds__(256) void proj_gemm(const float* __restrict__ A,
                                                 const u16* __restrict__ Bh,
                                                 const u16* __restrict__ Bl,
                                                 u16* __restrict__ outh,
                                                 u16* __restrict__ outl,
                                                 int M, int K, int N, float scale) {
  int rb = blockIdx.x, b = blockIdx.z;
  int wave = threadIdx.x >> 6, lane = threadIdx.x & 63;
  int lr = lane & 15, lg = lane >> 4;
  int row0 = rb * 64 + wave * 16;

  const float* Arow = A + (size_t)(row0 + lr) * K;
  const u16* Bhb = Bh + (size_t)b * N * K;
  const u16* Blb = Bl + (size_t)b * N * K;

  f32x4 acc[4] = {};
  for (int k0 = 0; k0 < K; k0 += 32) {
    float4 a0 = *(const float4*)(Arow + k0 + lg * 8);
    float4 a1 = *(const float4*)(Arow + k0 + lg * 8 + 4);
    float av[8] = {a0.x, a0.y, a0.z, a0.w, a1.x, a1.y, a1.z, a1.w};
    bf16x8 ah, al;
#pragma unroll
    for (int j = 0; j < 8; ++j) {
      u16 hh = f2bf(av[j]);
      ah[j] = (short)hh;
      al[j] = (short)f2bf(av[j] - bf2f(hh));
    }
#pragma unroll
    for (int ct = 0; ct < 4; ++ct) {
      size_t boff = (size_t)(ct * 16 + lr) * K + k0 + lg * 8;
      bf16x8 bh = *(const bf16x8*)(Bhb + boff);
      acc[ct] = __builtin_amdgcn_mfma_f32_16x16x32_bf16(ah, bh, acc[ct], 0, 0, 0);
      acc[ct] = __builtin_amdgcn_mfma_f32_16x16x32_bf16(al, bh, acc[ct], 0, 0, 0);
      bf16x8 bl = *(const bf16x8*)(Blb + boff);
      acc[ct] = __builtin_amdgcn_mfma_f32_16x16x32_bf16(ah, bl, acc[ct], 0, 0, 0);
    }
  }
#pragma unroll
  for (int ct = 0; ct < 4; ++ct)
#pragma unroll
    for (int r = 0; r < 4; ++r) {
      float v = acc[ct][r] * scale;
      int row = row0 + lg * 4 + r;
      int col = ct * 16 + lr;
      if (MODE == 0) {
        size_t idx = ((size_t)b * M + row) * N + col;
        u16 hh = f2bf(v);
        outh[idx] = hh;
        outl[idx] = f2bf(v - bf2f(hh));
      } else {
        outh[((size_t)b * N + col) * M + row] = f2bf(v);
      }
    }
}

// ---------------- flash attention (split-KV x2) ----------------
// qh,ql,kh,kl: [8][4096][64] bf16 (q pre-scaled 1/8); vT: [8][64][4096] bf16
// Opart: [2][8][4096][64] bf16 unnormalized; ml: [2][8][4096] float2 (m, l)
__global__ __launch_bounds__(256) void attn_kernel(const u16* __restrict__ qhh,
                                                   const u16* __restrict__ qhl,
                                                   const u16* __restrict__ khh,
                                                   const u16* __restrict__ khl,
                                                   const u16* __restrict__ vT,
                                                   u16* __restrict__ Opart,
                                                   float2* __restrict__ ml) {
  const int n = 4096, d = 64;
  int qb = blockIdx.x, h = blockIdx.y, half = blockIdx.z;
  int wave = threadIdx.x >> 6, lane = threadIdx.x & 63;
  int lr = lane & 15, lg = lane >> 4;
  int t = threadIdx.x;

  __shared__ u16 KH[64 * 64];
  __shared__ u16 KL[64 * 64];
  __shared__ u16 VS[64 * 64];
  __shared__ u16 PS[4 * 16 * 64];

  int qrow0 = qb * 64 + wave * 16;
  bf16x8 qfh[2], qfl[2];
#pragma unroll
  for (int ks = 0; ks < 2; ++ks) {
    size_t qoff = ((size_t)h * n + qrow0 + lr) * d + ks * 32 + lg * 8;
    qfh[ks] = *(const bf16x8*)(qhh + qoff);
    qfl[ks] = *(const bf16x8*)(qhl + qoff);
  }

  f32x4 accO[4] = {};
  float m[4], l[4];
#pragma unroll
  for (int r = 0; r < 4; ++r) { m[r] = -INFINITY; l[r] = 0.f; }

  int rr = t >> 3, cw = (t & 7) * 16;  // staging: row rr(+32), 16B chunk cw
  const u16* khsrc0 = khh + (size_t)h * n * d;
  const u16* klsrc0 = khl + (size_t)h * n * d;
  const u16* vsrc0 = vT + (size_t)h * d * n;
  char* Pw = (char*)PS + wave * 2048;

  int kv_begin = half * 2048, kv_end = kv_begin + 2048;
  for (int kv0 = kv_begin; kv0 < kv_end; kv0 += 64) {
    const u16* khs = khsrc0 + (size_t)kv0 * d;
    const u16* kls = klsrc0 + (size_t)kv0 * d;
    const u16* vs = vsrc0 + kv0;
    *(bf16x8*)((char*)KH + SWZ(rr, cw))      = *(const bf16x8*)(khs + (size_t)rr * d + (t & 7) * 8);
    *(bf16x8*)((char*)KH + SWZ(rr + 32, cw)) = *(const bf16x8*)(khs + (size_t)(rr + 32) * d + (t & 7) * 8);
    *(bf16x8*)((char*)KL + SWZ(rr, cw))      = *(const bf16x8*)(kls + (size_t)rr * d + (t & 7) * 8);
    *(bf16x8*)((char*)KL + SWZ(rr + 32, cw)) = *(const bf16x8*)(kls + (size_t)(rr + 32) * d + (t & 7) * 8);
    *(bf16x8*)((char*)VS + SWZ(rr, cw))      = *(const bf16x8*)(vs + (size_t)rr * n + (t & 7) * 8);
    *(bf16x8*)((char*)VS + SWZ(rr + 32, cw)) = *(const bf16x8*)(vs + (size_t)(rr + 32) * n + (t & 7) * 8);
    __syncthreads();

    // S = (q_hi+q_lo)(K_hi+K_lo)^T, dropping lo*lo
    f32x4 s[4] = {};
#pragma unroll
    for (int ct = 0; ct < 4; ++ct) {
      int R = ct * 16 + lr;
#pragma unroll
      for (int ks = 0; ks < 2; ++ks) {
        bf16x8 bh = *(const bf16x8*)((char*)KH + SWZ(R, ks * 64 + lg * 16));
        s[ct] = __builtin_amdgcn_mfma_f32_16x16x32_bf16(qfh[ks], bh, s[ct], 0, 0, 0);
        s[ct] = __builtin_amdgcn_mfma_f32_16x16x32_bf16(qfl[ks], bh, s[ct], 0, 0, 0);
        bf16x8 bl = *(const bf16x8*)((char*)KL + SWZ(R, ks * 64 + lg * 16));
        s[ct] = __builtin_amdgcn_mfma_f32_16x16x32_bf16(qfh[ks], bl, s[ct], 0, 0, 0);
      }
    }

    // online softmax; lane owns q-rows lg*4+r at key col lr (+16*ct)
#pragma unroll
    for (int r = 0; r < 4; ++r) {
      float mx = fmaxf(fmaxf(s[0][r], s[1][r]), fmaxf(s[2][r], s[3][r]));
#pragma unroll
      for (int msk = 1; msk < 16; msk <<= 1) mx = fmaxf(mx, __shfl_xor(mx, msk));
      float mn = fmaxf(m[r], mx);
      float alpha = __expf(m[r] - mn);
      m[r] = mn;
      float rs = 0.f;
#pragma unroll
      for (int ct = 0; ct < 4; ++ct) {
        float p = __expf(s[ct][r] - mn);
        s[ct][r] = p;
        rs += p;
      }
#pragma unroll
      for (int msk = 1; msk < 16; msk <<= 1) rs += __shfl_xor(rs, msk);
      l[r] = l[r] * alpha + rs;
#pragma unroll
      for (int dt = 0; dt < 4; ++dt) accO[dt][r] *= alpha;
    }

    // P -> wave-private LDS (swizzled), repack into A-fragment layout
#pragma unroll
    for (int ct = 0; ct < 4; ++ct)
#pragma unroll
      for (int r = 0; r < 4; ++r) {
        int prow = lg * 4 + r;
        *(u16*)(Pw + SWZ(prow, (ct * 16 + lr) * 2)) = f2bf(s[ct][r]);
      }

    bf16x8 pa[2];
    pa[0] = *(const bf16x8*)(Pw + SWZ(lr, 0 + lg * 16));
    pa[1] = *(const bf16x8*)(Pw + SWZ(lr, 64 + lg * 16));

    // O += P @ V
#pragma unroll
    for (int dt = 0; dt < 4; ++dt) {
      int R = dt * 16 + lr;
#pragma unroll
      for (int ks = 0; ks < 2; ++ks) {
        bf16x8 vf = *(const bf16x8*)((char*)VS + SWZ(R, ks * 64 + lg * 16));
        accO[dt] = __builtin_amdgcn_mfma_f32_16x16x32_bf16(pa[ks], vf, accO[dt], 0, 0, 0);
      }
    }
    __syncthreads();
  }

  // epilogue: store unnormalized O (bf16) + (m,l) per row
  u16* Ob = Opart + (((size_t)half * 8 + h) * n) * d;
  float2* mlp = ml + ((size_t)half * 8 + h) * n;
#pragma unroll
  for (int r = 0; r < 4; ++r) {
    int row = qrow0 + lg * 4 + r;
#pragma unroll
    for (int dt = 0; dt < 4; ++dt)
      Ob[(size_t)row * d + dt * 16 + lr] = f2bf(accO[dt][r]);
    if (lr == 0) mlp[row] = make_float2(m[r], l[r]);
  }
}

// ---------------- combine the two KV halves ----------------
__global__ __launch_bounds__(256) void attn_combine(const u16* __restrict__ Opart,
                                                    const float2* __restrict__ ml,
                                                    u16* __restrict__ att) {
  int tid = blockIdx.x * 256 + threadIdx.x;  // 4096*8*8 = 262144 threads
  int chunk = tid & 7;
  int h = (tid >> 3) & 7;
  int row = tid >> 6;
  float2 ml0 = ml[(size_t)h * 4096 + row];
  float2 ml1 = ml[(size_t)(8 + h) * 4096 + row];
  float mstar = fmaxf(ml0.x, ml1.x);
  float w0 = __expf(ml0.x - mstar), w1 = __expf(ml1.x - mstar);
  float inv = 1.f / (ml0.y * w0 + ml1.y * w1);
  w0 *= inv; w1 *= inv;
  bf16x8 o0 = *(const bf16x8*)(Opart + ((size_t)h * 4096 + row) * 64 + chunk * 8);
  bf16x8 o1 = *(const bf16x8*)(Opart + ((size_t)(8 + h) * 4096 + row) * 64 + chunk * 8);
  bf16x8 res;
#pragma unroll
  for (int j = 0; j < 8; ++j)
    res[j] = (short)f2bf(bf2f((u16)o0[j]) * w0 + bf2f((u16)o1[j]) * w1);
  *(bf16x8*)(att + (size_t)row * 512 + h * 64 + chunk * 8) = res;
}

// ---------------- final projection: out = att @ WoT^T (fp32 out) ----------------
__global__ __launch_bounds__(256) void final_gemm(const u16* __restrict__ A,
                                                  const u16* __restrict__ BT,
                                                  float* __restrict__ out,
                                                  int M, int K, int N) {
  int rb = blockIdx.x, cb = blockIdx.y;
  int wave = threadIdx.x >> 6, lane = threadIdx.x & 63;
  int lr = lane & 15, lg = lane >> 4;
  int row0 = rb * 64 + wave * 16;

  const u16* Arow = A + (size_t)(row0 + lr) * K;
  const u16* Bbase = BT + (size_t)(cb * 64) * K;

  f32x4 acc[4] = {};
  for (int k0 = 0; k0 < K; k0 += 32) {
    bf16x8 a = *(const bf16x8*)(Arow + k0 + lg * 8);
#pragma unroll
    for (int ct = 0; ct < 4; ++ct) {
      bf16x8 bf = *(const bf16x8*)(Bbase + (size_t)(ct * 16 + lr) * K + k0 + lg * 8);
      acc[ct] = __builtin_amdgcn_mfma_f32_16x16x32_bf16(a, bf, acc[ct], 0, 0, 0);
    }
  }
#pragma unroll
  for (int ct = 0; ct < 4; ++ct)
#pragma unroll
    for (int r = 0; r < 4; ++r)
      out[(size_t)(row0 + lg * 4 + r) * N + cb * 64 + ct * 16 + lr] = acc[ct][r];
}

// ---------------- launch ----------------
extern "C" void kernel_launch(void* const* d_in, const int* in_sizes, int n_in,
                              void* d_out, int out_size, void* d_ws, size_t ws_size,
                              hipStream_t stream) {
  const float* Q = (const float*)d_in[0];
  const float* K = (const float*)d_in[1];
  const float* V = (const float*)d_in[2];
  const float* Wq = (const float*)d_in[3];
  const float* Wk = (const float*)d_in[4];
  const float* Wv = (const float*)d_in[5];
  const float* Wo = (const float*)d_in[6];
  float* out = (float*)d_out;

  const int n = 4096, dim = 512, h = 8, d = 64;
  const size_t KB = 1 << 10, MB = 1 << 20;
  char* ws = (char*)d_ws;
  u16* qhh  = (u16*)(ws + 0 * MB);    // 4 MB each
  u16* qhl  = (u16*)(ws + 4 * MB);
  u16* khh  = (u16*)(ws + 8 * MB);
  u16* khl  = (u16*)(ws + 12 * MB);
  u16* vTp  = (u16*)(ws + 16 * MB);
  u16* WqTh = (u16*)(ws + 20 * MB);   // 512 KB each
  u16* WqTl = (u16*)(ws + 20 * MB + 512 * KB);
  u16* WkTh = (u16*)(ws + 21 * MB);
  u16* WkTl = (u16*)(ws + 21 * MB + 512 * KB);
  u16* WvTh = (u16*)(ws + 22 * MB);
  u16* WvTl = (u16*)(ws + 22 * MB + 512 * KB);
  u16* WoT  = (u16*)(ws + 23 * MB);   // 512 KB
  float2* ml = (float2*)(ws + 23 * MB + 512 * KB);  // 512 KB
  u16* Opart = (u16*)(ws + 24 * MB);  // 8 MB -> ends at 32 MB
  u16* att  = qhh;  // reused after attn

  int wtot = h * dim * d;
  transpose_split_cvt<<<(wtot + 255) / 256, 256, 0, stream>>>(Wq, WqTh, WqTl, dim, d, wtot);
  transpose_split_cvt<<<(wtot + 255) / 256, 256, 0, stream>>>(Wk, WkTh, WkTl, dim, d, wtot);
  transpose_split_cvt<<<(wtot + 255) / 256, 256, 0, stream>>>(Wv, WvTh, WvTl, dim, d, wtot);
  int wo_tot = dim * dim;
  transpose_cvt<<<(wo_tot + 255) / 256, 256, 0, stream>>>(Wo, WoT, dim, dim, wo_tot);

  dim3 gp(n / 64, 1, h);
  proj_gemm<0><<<gp, 256, 0, stream>>>(Q, WqTh, WqTl, qhh, qhl, n, dim, d, 0.125f);
  proj_gemm<0><<<gp, 256, 0, stream>>>(K, WkTh, WkTl, khh, khl, n, dim, d, 1.0f);
  proj_gemm<1><<<gp, 256, 0, stream>>>(V, WvTh, WvTl, vTp, nullptr, n, dim, d, 1.0f);

  attn_kernel<<<dim3(n / 64, h, 2), 256, 0, stream>>>(qhh, qhl, khh, khl, vTp, Opart, ml);
  attn_combine<<<(n * h * 8) / 256, 256, 0, stream>>>(Opart, ml, att);

  final_gemm<<<dim3(n / 64, dim / 64), 256, 0, stream>>>(att, WoT, out, n, dim, dim);
}

// Round 4
// 256.146 us; speedup vs baseline: 1.6284x; 1.2548x over previous
//
#include <hip/hip_runtime.h>

// MultiHeadAttentionLayer: n=4096, dim=512, h=8, d=64, fp32 in/out.
// bf16 MFMA + Dekker split upstream of softmax. R4: swapped QK^T (lane owns a
// q-row -> in-register softmax, 2 shfls), in-lane P pack via v_cvt_pk_bf16_f32
// with a permuted logical-key map matched by V's b64 reads (no P LDS, no lane
// exchange), and launch fusion (9 -> 5 dispatches).

typedef __attribute__((ext_vector_type(8))) short bf16x8;
typedef __attribute__((ext_vector_type(4))) float f32x4;
typedef unsigned short u16;

static __device__ __forceinline__ u16 f2bf(float f) {
  union { float f; unsigned u; } v; v.f = f;
  unsigned r = v.u + 0x7fffu + ((v.u >> 16) & 1u);
  return (u16)(r >> 16);
}
static __device__ __forceinline__ float bf2f(u16 h) {
  union { unsigned u; float f; } v; v.u = ((unsigned)h) << 16; return v.f;
}
static __device__ __forceinline__ unsigned cvt_pk_bf16(float lo, float hi) {
  unsigned r;
  asm("v_cvt_pk_bf16_f32 %0, %1, %2" : "=v"(r) : "v"(lo), "v"(hi));
  return r;
}

// byte address of (row, byteoff) in a row-stride-128B LDS tile, XOR-swizzled.
#define SWZ(row, byteoff) ((((row) * 128) + (byteoff)) ^ (((row) & 7) << 4))

// ---------------- weight prep: all 4 transposes in one kernel ----------------
// Wall_h/Wall_l: [3][8][64][512] split bf16 (Wq,Wk,Wv transposed per head)
// WoT: [512][512] bf16 (Wo transposed)
__global__ __launch_bounds__(256) void prep_weights(const float* __restrict__ Wq,
                                                    const float* __restrict__ Wk,
                                                    const float* __restrict__ Wv,
                                                    const float* __restrict__ Wo,
                                                    u16* __restrict__ Wall_h,
                                                    u16* __restrict__ Wall_l,
                                                    u16* __restrict__ WoT) {
  int i = blockIdx.x * 256 + threadIdx.x;
  if (i < 786432) {
    int which = i / 262144, rem = i - which * 262144;
    int b = rem >> 15, r2 = rem & 32767;
    int c = r2 >> 9, r = r2 & 511;
    const float* W = which == 0 ? Wq : which == 1 ? Wk : Wv;
    float x = W[(b << 15) + r * 64 + c];
    u16 h = f2bf(x);
    Wall_h[i] = h;
    Wall_l[i] = f2bf(x - bf2f(h));
  } else if (i < 786432 + 262144) {
    int rem = i - 786432;
    int c = rem >> 9, r = rem & 511;
    WoT[rem] = f2bf(Wo[r * 512 + c]);
  }
}

// ------------- fused projection GEMM (q,k,v in one launch) -------------
// grid (64, 24): y = which*8 + head. which 0: q (scale 1/8, split out),
// 1: k (split out), 2: v (plain out, transposed [h][d][n]).
__global__ __launch_bounds__(256) void proj_gemm(const float* __restrict__ Q,
                                                 const float* __restrict__ Kin,
                                                 const float* __restrict__ Vin,
                                                 const u16* __restrict__ Wall_h,
                                                 const u16* __restrict__ Wall_l,
                                                 u16* __restrict__ qhh, u16* __restrict__ qhl,
                                                 u16* __restrict__ khh, u16* __restrict__ khl,
                                                 u16* __restrict__ vTp) {
  const int n = 4096, K = 512, N = 64;
  int rb = blockIdx.x;
  int which = blockIdx.y >> 3, b = blockIdx.y & 7;
  int wave = threadIdx.x >> 6, lane = threadIdx.x & 63;
  int lr = lane & 15, lg = lane >> 4;
  int row0 = rb * 64 + wave * 16;

  const float* A = which == 0 ? Q : which == 1 ? Kin : Vin;
  const u16* Bh = Wall_h + (size_t)(which * 8 + b) * (N * K);
  const u16* Bl = Wall_l + (size_t)(which * 8 + b) * (N * K);
  float scale = which == 0 ? 0.125f : 1.0f;

  const float* Arow = A + (size_t)(row0 + lr) * K;

  f32x4 acc[4] = {};
  for (int k0 = 0; k0 < K; k0 += 32) {
    float4 a0 = *(const float4*)(Arow + k0 + lg * 8);
    float4 a1 = *(const float4*)(Arow + k0 + lg * 8 + 4);
    float av[8] = {a0.x, a0.y, a0.z, a0.w, a1.x, a1.y, a1.z, a1.w};
    bf16x8 ah, al;
#pragma unroll
    for (int j = 0; j < 8; ++j) {
      u16 hh = f2bf(av[j]);
      ah[j] = (short)hh;
      al[j] = (short)f2bf(av[j] - bf2f(hh));
    }
#pragma unroll
    for (int ct = 0; ct < 4; ++ct) {
      size_t boff = (size_t)(ct * 16 + lr) * K + k0 + lg * 8;
      bf16x8 bh = *(const bf16x8*)(Bh + boff);
      acc[ct] = __builtin_amdgcn_mfma_f32_16x16x32_bf16(ah, bh, acc[ct], 0, 0, 0);
      acc[ct] = __builtin_amdgcn_mfma_f32_16x16x32_bf16(al, bh, acc[ct], 0, 0, 0);
      bf16x8 bl = *(const bf16x8*)(Bl + boff);
      acc[ct] = __builtin_amdgcn_mfma_f32_16x16x32_bf16(ah, bl, acc[ct], 0, 0, 0);
    }
  }
#pragma unroll
  for (int ct = 0; ct < 4; ++ct)
#pragma unroll
    for (int r = 0; r < 4; ++r) {
      float v = acc[ct][r] * scale;
      int row = row0 + lg * 4 + r;
      int col = ct * 16 + lr;
      if (which == 2) {
        vTp[((size_t)b * N + col) * n + row] = f2bf(v);
      } else {
        size_t idx = ((size_t)b * n + row) * N + col;
        u16 hh = f2bf(v);
        if (which == 0) { qhh[idx] = hh; qhl[idx] = f2bf(v - bf2f(hh)); }
        else            { khh[idx] = hh; khl[idx] = f2bf(v - bf2f(hh)); }
      }
    }
}

// ---------------- flash attention (swapped QK^T, split-KV x2) ----------------
// qh,ql,kh,kl: [8][4096][64] bf16 (q pre-scaled 1/8); vT: [8][64][4096] bf16
// Opart: [2][8][4096][64] bf16 unnormalized; ml: [2][8][4096] float2 (m, l)
__global__ __launch_bounds__(256) void attn_kernel(const u16* __restrict__ qhh,
                                                   const u16* __restrict__ qhl,
                                                   const u16* __restrict__ khh,
                                                   const u16* __restrict__ khl,
                                                   const u16* __restrict__ vT,
                                                   u16* __restrict__ Opart,
                                                   float2* __restrict__ ml) {
  const int n = 4096, d = 64;
  int qb = blockIdx.x, h = blockIdx.y, half = blockIdx.z;
  int wave = threadIdx.x >> 6, lane = threadIdx.x & 63;
  int c = lane & 15, g = lane >> 4;
  int t = threadIdx.x;

  __shared__ u16 KH[64 * 64];
  __shared__ u16 KL[64 * 64];
  __shared__ u16 VS[64 * 64];
  char* KHb = (char*)KH;
  char* KLb = (char*)KL;
  char* VSb = (char*)VS;

  int qrow0 = qb * 64 + wave * 16;
  // Q fragments (B-operand layout == A-operand layout: row=lane&15, k=g*8+j)
  bf16x8 qfh[2], qfl[2];
#pragma unroll
  for (int ks = 0; ks < 2; ++ks) {
    size_t qoff = ((size_t)h * n + qrow0 + c) * d + ks * 32 + g * 8;
    qfh[ks] = *(const bf16x8*)(qhh + qoff);
    qfl[ks] = *(const bf16x8*)(qhl + qoff);
  }

  f32x4 accO[4] = {};
  float m = -INFINITY, l = 0.f;

  int rr = t >> 3, cw = (t & 7) * 16;
  const u16* khsrc0 = khh + (size_t)h * n * d;
  const u16* klsrc0 = khl + (size_t)h * n * d;
  const u16* vsrc0 = vT + (size_t)h * d * n;

  int kv_begin = half * 2048, kv_end = kv_begin + 2048;
  for (int kv0 = kv_begin; kv0 < kv_end; kv0 += 64) {
    const u16* khs = khsrc0 + (size_t)kv0 * d;
    const u16* kls = klsrc0 + (size_t)kv0 * d;
    const u16* vs = vsrc0 + kv0;
    *(bf16x8*)(KHb + SWZ(rr, cw))      = *(const bf16x8*)(khs + (size_t)rr * d + (t & 7) * 8);
    *(bf16x8*)(KHb + SWZ(rr + 32, cw)) = *(const bf16x8*)(khs + (size_t)(rr + 32) * d + (t & 7) * 8);
    *(bf16x8*)(KLb + SWZ(rr, cw))      = *(const bf16x8*)(kls + (size_t)rr * d + (t & 7) * 8);
    *(bf16x8*)(KLb + SWZ(rr + 32, cw)) = *(const bf16x8*)(kls + (size_t)(rr + 32) * d + (t & 7) * 8);
    *(bf16x8*)(VSb + SWZ(rr, cw))      = *(const bf16x8*)(vs + (size_t)rr * n + (t & 7) * 8);
    *(bf16x8*)(VSb + SWZ(rr + 32, cw)) = *(const bf16x8*)(vs + (size_t)(rr + 32) * n + (t & 7) * 8);
    __syncthreads();

    // S^T = K @ Q^T (swapped): s[ct] reg r = P~[key=ct*16+g*4+r][q=c]
    f32x4 s[4] = {};
#pragma unroll
    for (int ct = 0; ct < 4; ++ct) {
      int R = ct * 16 + c;
#pragma unroll
      for (int ks = 0; ks < 2; ++ks) {
        bf16x8 kh_f = *(const bf16x8*)(KHb + SWZ(R, ks * 64 + g * 16));
        s[ct] = __builtin_amdgcn_mfma_f32_16x16x32_bf16(kh_f, qfh[ks], s[ct], 0, 0, 0);
        s[ct] = __builtin_amdgcn_mfma_f32_16x16x32_bf16(kh_f, qfl[ks], s[ct], 0, 0, 0);
        bf16x8 kl_f = *(const bf16x8*)(KLb + SWZ(R, ks * 64 + g * 16));
        s[ct] = __builtin_amdgcn_mfma_f32_16x16x32_bf16(kl_f, qfh[ks], s[ct], 0, 0, 0);
      }
    }

    // in-register online softmax for q-row c (16 values in-lane + 4 lanes)
    float mx0 = fmaxf(fmaxf(s[0][0], s[0][1]), fmaxf(s[0][2], s[0][3]));
    float mx1 = fmaxf(fmaxf(s[1][0], s[1][1]), fmaxf(s[1][2], s[1][3]));
    float mx2 = fmaxf(fmaxf(s[2][0], s[2][1]), fmaxf(s[2][2], s[2][3]));
    float mx3 = fmaxf(fmaxf(s[3][0], s[3][1]), fmaxf(s[3][2], s[3][3]));
    float mx = fmaxf(fmaxf(mx0, mx1), fmaxf(mx2, mx3));
    mx = fmaxf(mx, __shfl_xor(mx, 16));
    mx = fmaxf(mx, __shfl_xor(mx, 32));
    float mn = fmaxf(m, mx);
    float alpha = __expf(m - mn);
    m = mn;
    float rs = 0.f;
#pragma unroll
    for (int ct = 0; ct < 4; ++ct) {
      float p0 = __expf(s[ct][0] - mn);
      float p1 = __expf(s[ct][1] - mn);
      float p2 = __expf(s[ct][2] - mn);
      float p3 = __expf(s[ct][3] - mn);
      s[ct][0] = p0; s[ct][1] = p1; s[ct][2] = p2; s[ct][3] = p3;
      rs += (p0 + p1) + (p2 + p3);
    }
    rs += __shfl_xor(rs, 16);
    rs += __shfl_xor(rs, 32);
    l = l * alpha + rs;

    // rescale accO rows (q = g*4+r) by alpha from lane (g*4+r)
#pragma unroll
    for (int r = 0; r < 4; ++r) {
      float ar = __shfl(alpha, g * 4 + r);
#pragma unroll
      for (int dt = 0; dt < 4; ++dt) accO[dt][r] *= ar;
    }

    // pack P in-lane: logical key of PV HW slot (ks; g, j) is
    // 16*(ks + 2*(j>>2)) + 4g + (j&3); lane's own (ct,r) data fills it exactly.
    union { unsigned w[4]; bf16x8 v; } pa[2];
#pragma unroll
    for (int ks = 0; ks < 2; ++ks) {
      pa[ks].w[0] = cvt_pk_bf16(s[ks][0], s[ks][1]);
      pa[ks].w[1] = cvt_pk_bf16(s[ks][2], s[ks][3]);
      pa[ks].w[2] = cvt_pk_bf16(s[ks + 2][0], s[ks + 2][1]);
      pa[ks].w[3] = cvt_pk_bf16(s[ks + 2][2], s[ks + 2][3]);
    }

    // O += P @ V  (V read at the permuted logical-key columns: two b64 each)
#pragma unroll
    for (int dt = 0; dt < 4; ++dt) {
      int R = dt * 16 + c;
#pragma unroll
      for (int ks = 0; ks < 2; ++ks) {
        union { uint2 u[2]; bf16x8 v; } vf;
        vf.u[0] = *(const uint2*)(VSb + SWZ(R, 32 * ks + 8 * g));
        vf.u[1] = *(const uint2*)(VSb + SWZ(R, 32 * ks + 8 * g + 64));
        accO[dt] = __builtin_amdgcn_mfma_f32_16x16x32_bf16(pa[ks].v, vf.v, accO[dt], 0, 0, 0);
      }
    }
    __syncthreads();
  }

  // epilogue: unnormalized O + (m,l)
  u16* Ob = Opart + (((size_t)half * 8 + h) * n) * d;
  float2* mlp = ml + ((size_t)half * 8 + h) * n;
#pragma unroll
  for (int r = 0; r < 4; ++r) {
    int row = qrow0 + g * 4 + r;
#pragma unroll
    for (int dt = 0; dt < 4; ++dt)
      Ob[(size_t)row * d + dt * 16 + c] = f2bf(accO[dt][r]);
  }
  if (g == 0) mlp[qrow0 + c] = make_float2(m, l);
}

// ---------------- combine the two KV halves ----------------
__global__ __launch_bounds__(256) void attn_combine(const u16* __restrict__ Opart,
                                                    const float2* __restrict__ ml,
                                                    u16* __restrict__ att) {
  int tid = blockIdx.x * 256 + threadIdx.x;  // 4096*8*8 threads
  int chunk = tid & 7;
  int h = (tid >> 3) & 7;
  int row = tid >> 6;
  float2 ml0 = ml[(size_t)h * 4096 + row];
  float2 ml1 = ml[(size_t)(8 + h) * 4096 + row];
  float mstar = fmaxf(ml0.x, ml1.x);
  float w0 = __expf(ml0.x - mstar), w1 = __expf(ml1.x - mstar);
  float inv = 1.f / (ml0.y * w0 + ml1.y * w1);
  w0 *= inv; w1 *= inv;
  bf16x8 o0 = *(const bf16x8*)(Opart + ((size_t)h * 4096 + row) * 64 + chunk * 8);
  bf16x8 o1 = *(const bf16x8*)(Opart + ((size_t)(8 + h) * 4096 + row) * 64 + chunk * 8);
  bf16x8 res;
#pragma unroll
  for (int j = 0; j < 8; ++j)
    res[j] = (short)f2bf(bf2f((u16)o0[j]) * w0 + bf2f((u16)o1[j]) * w1);
  *(bf16x8*)(att + (size_t)row * 512 + h * 64 + chunk * 8) = res;
}

// ---------------- final projection: out = att @ WoT^T (fp32 out) ----------------
__global__ __launch_bounds__(256) void final_gemm(const u16* __restrict__ A,
                                                  const u16* __restrict__ BT,
                                                  float* __restrict__ out,
                                                  int M, int K, int N) {
  int rb = blockIdx.x, cb = blockIdx.y;
  int wave = threadIdx.x >> 6, lane = threadIdx.x & 63;
  int lr = lane & 15, lg = lane >> 4;
  int row0 = rb * 64 + wave * 16;

  const u16* Arow = A + (size_t)(row0 + lr) * K;
  const u16* Bbase = BT + (size_t)(cb * 64) * K;

  f32x4 acc[4] = {};
  for (int k0 = 0; k0 < K; k0 += 32) {
    bf16x8 a = *(const bf16x8*)(Arow + k0 + lg * 8);
#pragma unroll
    for (int ct = 0; ct < 4; ++ct) {
      bf16x8 bf = *(const bf16x8*)(Bbase + (size_t)(ct * 16 + lr) * K + k0 + lg * 8);
      acc[ct] = __builtin_amdgcn_mfma_f32_16x16x32_bf16(a, bf, acc[ct], 0, 0, 0);
    }
  }
#pragma unroll
  for (int ct = 0; ct < 4; ++ct)
#pragma unroll
    for (int r = 0; r < 4; ++r)
      out[(size_t)(row0 + lg * 4 + r) * N + cb * 64 + ct * 16 + lr] = acc[ct][r];
}

// ---------------- launch ----------------
extern "C" void kernel_launch(void* const* d_in, const int* in_sizes, int n_in,
                              void* d_out, int out_size, void* d_ws, size_t ws_size,
                              hipStream_t stream) {
  const float* Q = (const float*)d_in[0];
  const float* K = (const float*)d_in[1];
  const float* V = (const float*)d_in[2];
  const float* Wq = (const float*)d_in[3];
  const float* Wk = (const float*)d_in[4];
  const float* Wv = (const float*)d_in[5];
  const float* Wo = (const float*)d_in[6];
  float* out = (float*)d_out;

  const int n = 4096, dim = 512;
  const size_t KB = 1 << 10, MB = 1 << 20;
  char* ws = (char*)d_ws;
  u16* qhh    = (u16*)(ws + 0 * MB);   // 4 MB each
  u16* qhl    = (u16*)(ws + 4 * MB);
  u16* khh    = (u16*)(ws + 8 * MB);
  u16* khl    = (u16*)(ws + 12 * MB);
  u16* vTp    = (u16*)(ws + 16 * MB);
  u16* Wall_h = (u16*)(ws + 20 * MB);              // 1.5 MB
  u16* Wall_l = (u16*)(ws + 20 * MB + 1536 * KB);  // 1.5 MB
  u16* WoT    = (u16*)(ws + 23 * MB);              // 512 KB
  float2* ml  = (float2*)(ws + 23 * MB + 512 * KB);  // 512 KB
  u16* Opart  = (u16*)(ws + 24 * MB);              // 8 MB -> ends at 32 MB
  u16* att    = qhh;  // reused after attn

  prep_weights<<<4096, 256, 0, stream>>>(Wq, Wk, Wv, Wo, Wall_h, Wall_l, WoT);

  proj_gemm<<<dim3(n / 64, 24), 256, 0, stream>>>(Q, K, V, Wall_h, Wall_l,
                                                  qhh, qhl, khh, khl, vTp);

  attn_kernel<<<dim3(n / 64, 8, 2), 256, 0, stream>>>(qhh, qhl, khh, khl, vTp, Opart, ml);
  attn_combine<<<(n * 8 * 8) / 256, 256, 0, stream>>>(Opart, ml, att);

  final_gemm<<<dim3(n / 64, dim / 64), 256, 0, stream>>>(att, WoT, out, n, dim, dim);
}

// Round 5
// 245.927 us; speedup vs baseline: 1.6961x; 1.0416x over previous
//
#include <hip/hip_runtime.h>

// MultiHeadAttentionLayer: n=4096, dim=512, h=8, d=64, fp32 in/out.
// bf16 MFMA + Dekker split upstream of softmax. R5: T14 async register-staged
// KV prefetch (hide L2/HBM latency under compute), sigma-permuted V storage so
// PV B-fragments are single conflict-free b128 reads, exact defer-rescale, and
// cvt_pk-based Dekker split in the projection GEMM.

typedef __attribute__((ext_vector_type(8))) short bf16x8;
typedef __attribute__((ext_vector_type(4))) float f32x4;
typedef unsigned short u16;

static __device__ __forceinline__ u16 f2bf(float f) {
  union { float f; unsigned u; } v; v.f = f;
  unsigned r = v.u + 0x7fffu + ((v.u >> 16) & 1u);
  return (u16)(r >> 16);
}
static __device__ __forceinline__ float bf2f(u16 h) {
  union { unsigned u; float f; } v; v.u = ((unsigned)h) << 16; return v.f;
}
static __device__ __forceinline__ unsigned cvt_pk_bf16(float lo, float hi) {
  unsigned r;
  asm("v_cvt_pk_bf16_f32 %0, %1, %2" : "=v"(r) : "v"(lo), "v"(hi));
  return r;
}
// Dekker split of (v0,v1) into packed bf16 hi word + lo word (RNE, exact lo).
static __device__ __forceinline__ void split2(float v0, float v1,
                                              unsigned& hw, unsigned& lw) {
  unsigned h = cvt_pk_bf16(v0, v1);
  float h0 = __uint_as_float(h << 16);
  float h1 = __uint_as_float(h & 0xffff0000u);
  hw = h;
  lw = cvt_pk_bf16(v0 - h0, v1 - h1);
}

// byte address of (row, byteoff) in a row-stride-128B LDS tile, XOR-swizzled.
#define SWZ(row, byteoff) ((((row) * 128) + (byteoff)) ^ (((row) & 7) << 4))

// sigma: key -> storage position within a 64-block (bit permutation) such that
// PV fragment (ks,g) reads keys kappa(ks,g,j)=16(ks+2(j>>2))+4g+(j&3) as 8
// contiguous storage cols 32ks+8g+j.
static __device__ __forceinline__ int sigma64(int k) {
  return (k & 3) | (((k >> 5) & 1) << 2) | (((k >> 2) & 3) << 3) | (((k >> 4) & 1) << 5);
}

// ---------------- weight prep: all 4 transposes in one kernel ----------------
__global__ __launch_bounds__(256) void prep_weights(const float* __restrict__ Wq,
                                                    const float* __restrict__ Wk,
                                                    const float* __restrict__ Wv,
                                                    const float* __restrict__ Wo,
                                                    u16* __restrict__ Wall_h,
                                                    u16* __restrict__ Wall_l,
                                                    u16* __restrict__ WoT) {
  int i = blockIdx.x * 256 + threadIdx.x;
  if (i < 786432) {
    int which = i / 262144, rem = i - which * 262144;
    int b = rem >> 15, r2 = rem & 32767;
    int c = r2 >> 9, r = r2 & 511;
    const float* W = which == 0 ? Wq : which == 1 ? Wk : Wv;
    float x = W[(b << 15) + r * 64 + c];
    u16 h = f2bf(x);
    Wall_h[i] = h;
    Wall_l[i] = f2bf(x - bf2f(h));
  } else if (i < 786432 + 262144) {
    int rem = i - 786432;
    int c = rem >> 9, r = rem & 511;
    WoT[rem] = f2bf(Wo[r * 512 + c]);
  }
}

// ------------- fused projection GEMM (q,k,v in one launch) -------------
// grid (64, 24): y = which*8 + head. which 0: q (scale 1/8, split out),
// 1: k (split out), 2: v (plain out, transposed [h][d][n], key-axis sigma-permuted).
__global__ __launch_bounds__(256) void proj_gemm(const float* __restrict__ Q,
                                                 const float* __restrict__ Kin,
                                                 const float* __restrict__ Vin,
                                                 const u16* __restrict__ Wall_h,
                                                 const u16* __restrict__ Wall_l,
                                                 u16* __restrict__ qhh, u16* __restrict__ qhl,
                                                 u16* __restrict__ khh, u16* __restrict__ khl,
                                                 u16* __restrict__ vTp) {
  const int n = 4096, K = 512, N = 64;
  int rb = blockIdx.x;
  int which = blockIdx.y >> 3, b = blockIdx.y & 7;
  int wave = threadIdx.x >> 6, lane = threadIdx.x & 63;
  int lr = lane & 15, lg = lane >> 4;
  int row0 = rb * 64 + wave * 16;

  const float* A = which == 0 ? Q : which == 1 ? Kin : Vin;
  const u16* Bh = Wall_h + (size_t)(which * 8 + b) * (N * K);
  const u16* Bl = Wall_l + (size_t)(which * 8 + b) * (N * K);
  float scale = which == 0 ? 0.125f : 1.0f;

  const float* Arow = A + (size_t)(row0 + lr) * K;

  union U8 { unsigned w[4]; bf16x8 v; };
  f32x4 acc[4] = {};
  for (int k0 = 0; k0 < K; k0 += 32) {
    float4 a0 = *(const float4*)(Arow + k0 + lg * 8);
    float4 a1 = *(const float4*)(Arow + k0 + lg * 8 + 4);
    U8 ah, al;
    split2(a0.x, a0.y, ah.w[0], al.w[0]);
    split2(a0.z, a0.w, ah.w[1], al.w[1]);
    split2(a1.x, a1.y, ah.w[2], al.w[2]);
    split2(a1.z, a1.w, ah.w[3], al.w[3]);
#pragma unroll
    for (int ct = 0; ct < 4; ++ct) {
      size_t boff = (size_t)(ct * 16 + lr) * K + k0 + lg * 8;
      bf16x8 bh = *(const bf16x8*)(Bh + boff);
      acc[ct] = __builtin_amdgcn_mfma_f32_16x16x32_bf16(ah.v, bh, acc[ct], 0, 0, 0);
      acc[ct] = __builtin_amdgcn_mfma_f32_16x16x32_bf16(al.v, bh, acc[ct], 0, 0, 0);
      bf16x8 bl = *(const bf16x8*)(Bl + boff);
      acc[ct] = __builtin_amdgcn_mfma_f32_16x16x32_bf16(ah.v, bl, acc[ct], 0, 0, 0);
    }
  }
#pragma unroll
  for (int ct = 0; ct < 4; ++ct)
#pragma unroll
    for (int r = 0; r < 4; ++r) {
      float v = acc[ct][r] * scale;
      int row = row0 + lg * 4 + r;
      int col = ct * 16 + lr;
      if (which == 2) {
        int prow = (row & ~63) | sigma64(row & 63);
        vTp[((size_t)b * N + col) * n + prow] = f2bf(v);
      } else {
        size_t idx = ((size_t)b * n + row) * N + col;
        u16 hh = f2bf(v);
        if (which == 0) { qhh[idx] = hh; qhl[idx] = f2bf(v - bf2f(hh)); }
        else            { khh[idx] = hh; khl[idx] = f2bf(v - bf2f(hh)); }
      }
    }
}

// ---------------- flash attention (swapped QK^T, split-KV x2) ----------------
// qh,ql,kh,kl: [8][4096][64] bf16 (q pre-scaled 1/8); vT: [8][64][4096] bf16
// (key axis sigma-permuted per 64-block).
// Opart: [2][8][4096][64] bf16 unnormalized; ml: [2][8][4096] float2 (m, l)
__global__ __launch_bounds__(256) void attn_kernel(const u16* __restrict__ qhh,
                                                   const u16* __restrict__ qhl,
                                                   const u16* __restrict__ khh,
                                                   const u16* __restrict__ khl,
                                                   const u16* __restrict__ vT,
                                                   u16* __restrict__ Opart,
                                                   float2* __restrict__ ml) {
  const int n = 4096, d = 64;
  int qb = blockIdx.x, h = blockIdx.y, half = blockIdx.z;
  int wave = threadIdx.x >> 6, lane = threadIdx.x & 63;
  int c = lane & 15, g = lane >> 4;
  int t = threadIdx.x;

  __shared__ u16 KH[64 * 64];
  __shared__ u16 KL[64 * 64];
  __shared__ u16 VS[64 * 64];
  char* KHb = (char*)KH;
  char* KLb = (char*)KL;
  char* VSb = (char*)VS;

  int qrow0 = qb * 64 + wave * 16;
  bf16x8 qfh[2], qfl[2];
#pragma unroll
  for (int ks = 0; ks < 2; ++ks) {
    size_t qoff = ((size_t)h * n + qrow0 + c) * d + ks * 32 + g * 8;
    qfh[ks] = *(const bf16x8*)(qhh + qoff);
    qfl[ks] = *(const bf16x8*)(qhl + qoff);
  }

  f32x4 accO[4] = {};
  float m = -INFINITY, l = 0.f;

  int rr = t >> 3, cb8 = (t & 7) * 8, cw = (t & 7) * 16;
  // per-lane staging source pointers (tile-relative)
  const u16* kA = khh + ((size_t)h * n + half * 2048 + rr) * d + cb8;
  const u16* lA = khl + ((size_t)h * n + half * 2048 + rr) * d + cb8;
  const u16* vA = vT + (size_t)h * d * n + (size_t)rr * n + half * 2048 + cb8;

  bf16x8 p0, p1, p2, p3, p4, p5;
#define ISSUE(kv0)                                            \
  do {                                                        \
    size_t ko = (size_t)(kv0) * d;                            \
    p0 = *(const bf16x8*)(kA + ko);                           \
    p1 = *(const bf16x8*)(kA + ko + 32 * d);                  \
    p2 = *(const bf16x8*)(lA + ko);                           \
    p3 = *(const bf16x8*)(lA + ko + 32 * d);                  \
    p4 = *(const bf16x8*)(vA + (kv0));                        \
    p5 = *(const bf16x8*)(vA + (kv0) + 32 * n);               \
  } while (0)

  ISSUE(0);
  for (int it = 0; it < 32; ++it) {
    // write prefetched tile to LDS (compiler inserts the vmcnt waits)
    *(bf16x8*)(KHb + SWZ(rr, cw)) = p0;
    *(bf16x8*)(KHb + SWZ(rr + 32, cw)) = p1;
    *(bf16x8*)(KLb + SWZ(rr, cw)) = p2;
    *(bf16x8*)(KLb + SWZ(rr + 32, cw)) = p3;
    *(bf16x8*)(VSb + SWZ(rr, cw)) = p4;
    *(bf16x8*)(VSb + SWZ(rr + 32, cw)) = p5;
    __syncthreads();
    if (it < 31) ISSUE((it + 1) * 64);  // prefetch next tile; latency hides under compute

    // S^T = K @ Q^T (swapped): s[ct] reg r = P~[key=ct*16+g*4+r][q=c]
    f32x4 s[4] = {};
#pragma unroll
    for (int ct = 0; ct < 4; ++ct) {
      int R = ct * 16 + c;
#pragma unroll
      for (int ks = 0; ks < 2; ++ks) {
        bf16x8 kh_f = *(const bf16x8*)(KHb + SWZ(R, ks * 64 + g * 16));
        s[ct] = __builtin_amdgcn_mfma_f32_16x16x32_bf16(kh_f, qfh[ks], s[ct], 0, 0, 0);
        s[ct] = __builtin_amdgcn_mfma_f32_16x16x32_bf16(kh_f, qfl[ks], s[ct], 0, 0, 0);
        bf16x8 kl_f = *(const bf16x8*)(KLb + SWZ(R, ks * 64 + g * 16));
        s[ct] = __builtin_amdgcn_mfma_f32_16x16x32_bf16(kl_f, qfh[ks], s[ct], 0, 0, 0);
      }
    }

    // in-register online softmax for q-row c
    float mx0 = fmaxf(fmaxf(s[0][0], s[0][1]), fmaxf(s[0][2], s[0][3]));
    float mx1 = fmaxf(fmaxf(s[1][0], s[1][1]), fmaxf(s[1][2], s[1][3]));
    float mx2 = fmaxf(fmaxf(s[2][0], s[2][1]), fmaxf(s[2][2], s[2][3]));
    float mx3 = fmaxf(fmaxf(s[3][0], s[3][1]), fmaxf(s[3][2], s[3][3]));
    float mx = fmaxf(fmaxf(mx0, mx1), fmaxf(mx2, mx3));
    mx = fmaxf(mx, __shfl_xor(mx, 16));
    mx = fmaxf(mx, __shfl_xor(mx, 32));
    bool need = mx > m;
    float mn = need ? mx : m;
    float rs = 0.f;
#pragma unroll
    for (int ct = 0; ct < 4; ++ct) {
      float q0 = __expf(s[ct][0] - mn);
      float q1 = __expf(s[ct][1] - mn);
      float q2 = __expf(s[ct][2] - mn);
      float q3 = __expf(s[ct][3] - mn);
      s[ct][0] = q0; s[ct][1] = q1; s[ct][2] = q2; s[ct][3] = q3;
      rs += (q0 + q1) + (q2 + q3);
    }
    rs += __shfl_xor(rs, 16);
    rs += __shfl_xor(rs, 32);

    if (__any(need)) {           // rescale only when some row's max grew (exact)
      float alpha = __expf(m - mn);
      m = mn;
      l = l * alpha + rs;
#pragma unroll
      for (int r = 0; r < 4; ++r) {
        float ar = __shfl(alpha, g * 4 + r);
#pragma unroll
        for (int dt = 0; dt < 4; ++dt) accO[dt][r] *= ar;
      }
    } else {
      l += rs;
    }

    // pack P in-lane: PV HW slot (ks; g, j) holds key 16*(ks+2*(j>>2))+4g+(j&3)
    union { unsigned w[4]; bf16x8 v; } pa[2];
#pragma unroll
    for (int ks = 0; ks < 2; ++ks) {
      pa[ks].w[0] = cvt_pk_bf16(s[ks][0], s[ks][1]);
      pa[ks].w[1] = cvt_pk_bf16(s[ks][2], s[ks][3]);
      pa[ks].w[2] = cvt_pk_bf16(s[ks + 2][0], s[ks + 2][1]);
      pa[ks].w[3] = cvt_pk_bf16(s[ks + 2][2], s[ks + 2][3]);
    }

    // O += P @ V : V stored sigma-permuted -> single b128 per fragment,
    // identical (conflict-free) pattern to the K reads.
#pragma unroll
    for (int dt = 0; dt < 4; ++dt) {
      int R = dt * 16 + c;
#pragma unroll
      for (int ks = 0; ks < 2; ++ks) {
        bf16x8 vf = *(const bf16x8*)(VSb + SWZ(R, ks * 64 + g * 16));
        accO[dt] = __builtin_amdgcn_mfma_f32_16x16x32_bf16(pa[ks].v, vf, accO[dt], 0, 0, 0);
      }
    }
    __syncthreads();
  }
#undef ISSUE

  // epilogue: unnormalized O + (m,l)
  u16* Ob = Opart + (((size_t)half * 8 + h) * n) * d;
  float2* mlp = ml + ((size_t)half * 8 + h) * n;
#pragma unroll
  for (int r = 0; r < 4; ++r) {
    int row = qrow0 + g * 4 + r;
#pragma unroll
    for (int dt = 0; dt < 4; ++dt)
      Ob[(size_t)row * d + dt * 16 + c] = f2bf(accO[dt][r]);
  }
  if (g == 0) mlp[qrow0 + c] = make_float2(m, l);
}

// ---------------- combine the two KV halves ----------------
__global__ __launch_bounds__(256) void attn_combine(const u16* __restrict__ Opart,
                                                    const float2* __restrict__ ml,
                                                    u16* __restrict__ att) {
  int tid = blockIdx.x * 256 + threadIdx.x;  // 4096*8*8 threads
  int chunk = tid & 7;
  int h = (tid >> 3) & 7;
  int row = tid >> 6;
  float2 ml0 = ml[(size_t)h * 4096 + row];
  float2 ml1 = ml[(size_t)(8 + h) * 4096 + row];
  float mstar = fmaxf(ml0.x, ml1.x);
  float w0 = __expf(ml0.x - mstar), w1 = __expf(ml1.x - mstar);
  float inv = 1.f / (ml0.y * w0 + ml1.y * w1);
  w0 *= inv; w1 *= inv;
  bf16x8 o0 = *(const bf16x8*)(Opart + ((size_t)h * 4096 + row) * 64 + chunk * 8);
  bf16x8 o1 = *(const bf16x8*)(Opart + ((size_t)(8 + h) * 4096 + row) * 64 + chunk * 8);
  bf16x8 res;
#pragma unroll
  for (int j = 0; j < 8; ++j)
    res[j] = (short)f2bf(bf2f((u16)o0[j]) * w0 + bf2f((u16)o1[j]) * w1);
  *(bf16x8*)(att + (size_t)row * 512 + h * 64 + chunk * 8) = res;
}

// ---------------- final projection: out = att @ WoT^T (fp32 out) ----------------
__global__ __launch_bounds__(256) void final_gemm(const u16* __restrict__ A,
                                                  const u16* __restrict__ BT,
                                                  float* __restrict__ out,
                                                  int M, int K, int N) {
  int rb = blockIdx.x, cb = blockIdx.y;
  int wave = threadIdx.x >> 6, lane = threadIdx.x & 63;
  int lr = lane & 15, lg = lane >> 4;
  int row0 = rb * 64 + wave * 16;

  const u16* Arow = A + (size_t)(row0 + lr) * K;
  const u16* Bbase = BT + (size_t)(cb * 64) * K;

  f32x4 acc[4] = {};
  for (int k0 = 0; k0 < K; k0 += 32) {
    bf16x8 a = *(const bf16x8*)(Arow + k0 + lg * 8);
#pragma unroll
    for (int ct = 0; ct < 4; ++ct) {
      bf16x8 bf = *(const bf16x8*)(Bbase + (size_t)(ct * 16 + lr) * K + k0 + lg * 8);
      acc[ct] = __builtin_amdgcn_mfma_f32_16x16x32_bf16(a, bf, acc[ct], 0, 0, 0);
    }
  }
#pragma unroll
  for (int ct = 0; ct < 4; ++ct)
#pragma unroll
    for (int r = 0; r < 4; ++r)
      out[(size_t)(row0 + lg * 4 + r) * N + cb * 64 + ct * 16 + lr] = acc[ct][r];
}

// ---------------- launch ----------------
extern "C" void kernel_launch(void* const* d_in, const int* in_sizes, int n_in,
                              void* d_out, int out_size, void* d_ws, size_t ws_size,
                              hipStream_t stream) {
  const float* Q = (const float*)d_in[0];
  const float* K = (const float*)d_in[1];
  const float* V = (const float*)d_in[2];
  const float* Wq = (const float*)d_in[3];
  const float* Wk = (const float*)d_in[4];
  const float* Wv = (const float*)d_in[5];
  const float* Wo = (const float*)d_in[6];
  float* out = (float*)d_out;

  const int n = 4096, dim = 512;
  const size_t KB = 1 << 10, MB = 1 << 20;
  char* ws = (char*)d_ws;
  u16* qhh    = (u16*)(ws + 0 * MB);   // 4 MB each
  u16* qhl    = (u16*)(ws + 4 * MB);
  u16* khh    = (u16*)(ws + 8 * MB);
  u16* khl    = (u16*)(ws + 12 * MB);
  u16* vTp    = (u16*)(ws + 16 * MB);
  u16* Wall_h = (u16*)(ws + 20 * MB);              // 1.5 MB
  u16* Wall_l = (u16*)(ws + 20 * MB + 1536 * KB);  // 1.5 MB
  u16* WoT    = (u16*)(ws + 23 * MB);              // 512 KB
  float2* ml  = (float2*)(ws + 23 * MB + 512 * KB);  // 512 KB
  u16* Opart  = (u16*)(ws + 24 * MB);              // 8 MB -> ends at 32 MB
  u16* att    = qhh;  // reused after attn

  prep_weights<<<4096, 256, 0, stream>>>(Wq, Wk, Wv, Wo, Wall_h, Wall_l, WoT);

  proj_gemm<<<dim3(n / 64, 24), 256, 0, stream>>>(Q, K, V, Wall_h, Wall_l,
                                                  qhh, qhl, khh, khl, vTp);

  attn_kernel<<<dim3(n / 64, 8, 2), 256, 0, stream>>>(qhh, qhl, khh, khl, vTp, Opart, ml);
  attn_combine<<<(n * 8 * 8) / 256, 256, 0, stream>>>(Opart, ml, att);

  final_gemm<<<dim3(n / 64, dim / 64), 256, 0, stream>>>(att, WoT, out, n, dim, dim);
}

// Round 6
// 177.496 us; speedup vs baseline: 2.3500x; 1.3855x over previous
//
#include <hip/hip_runtime.h>

// MultiHeadAttentionLayer: n=4096, dim=512, h=8, d=64, fp32 in/out.
// bf16 MFMA + Dekker split upstream of softmax. R6: proj/final GEMMs get
// fragment-packed weights (wave B-load = one contiguous 1KB line) + explicit
// 1-step register prefetch pipeline (R5's proj was latency-serialized at
// VGPR=24, MfmaUtil 6%). Attn/combine unchanged from R5.

typedef __attribute__((ext_vector_type(8))) short bf16x8;
typedef __attribute__((ext_vector_type(4))) float f32x4;
typedef unsigned short u16;

static __device__ __forceinline__ u16 f2bf(float f) {
  union { float f; unsigned u; } v; v.f = f;
  unsigned r = v.u + 0x7fffu + ((v.u >> 16) & 1u);
  return (u16)(r >> 16);
}
static __device__ __forceinline__ float bf2f(u16 h) {
  union { unsigned u; float f; } v; v.u = ((unsigned)h) << 16; return v.f;
}
static __device__ __forceinline__ unsigned cvt_pk_bf16(float lo, float hi) {
  unsigned r;
  asm("v_cvt_pk_bf16_f32 %0, %1, %2" : "=v"(r) : "v"(lo), "v"(hi));
  return r;
}
// Dekker split of (v0,v1) into packed bf16 hi word + lo word (RNE, exact lo).
static __device__ __forceinline__ void split2(float v0, float v1,
                                              unsigned& hw, unsigned& lw) {
  unsigned h = cvt_pk_bf16(v0, v1);
  float h0 = __uint_as_float(h << 16);
  float h1 = __uint_as_float(h & 0xffff0000u);
  hw = h;
  lw = cvt_pk_bf16(v0 - h0, v1 - h1);
}

// byte address of (row, byteoff) in a row-stride-128B LDS tile, XOR-swizzled.
#define SWZ(row, byteoff) ((((row) * 128) + (byteoff)) ^ (((row) & 7) << 4))

// sigma: key -> storage position within a 64-block (bit permutation) such that
// PV fragment (ks,g) reads keys kappa(ks,g,j)=16(ks+2(j>>2))+4g+(j&3) as 8
// contiguous storage cols 32ks+8g+j.
static __device__ __forceinline__ int sigma64(int k) {
  return (k & 3) | (((k >> 5) & 1) << 2) | (((k >> 2) & 3) << 3) | (((k >> 4) & 1) << 5);
}

// ---------------- weight prep ----------------
// Wall_h/Wall_l: per (which,head) 32768 u16 in FRAGMENT order:
//   off = ((k>>5)*4 + col>>4)*512 + (((k&31)>>3)*16 + (col&15))*8 + (k&7)
// WoTp: per col-block cb (64 cols) 32768 u16, same fragment order.
__global__ __launch_bounds__(256) void prep_weights(const float* __restrict__ Wq,
                                                    const float* __restrict__ Wk,
                                                    const float* __restrict__ Wv,
                                                    const float* __restrict__ Wo,
                                                    u16* __restrict__ Wall_h,
                                                    u16* __restrict__ Wall_l,
                                                    u16* __restrict__ WoTp) {
  int i = blockIdx.x * 256 + threadIdx.x;
  if (i < 786432) {
    int which = i / 262144, rem = i - which * 262144;
    int b = rem >> 15, r2 = rem & 32767;
    int c = r2 >> 9, r = r2 & 511;  // c: out col 0..63, r: k 0..511
    const float* W = which == 0 ? Wq : which == 1 ? Wk : Wv;
    float x = W[(b << 15) + r * 64 + c];
    u16 h = f2bf(x);
    size_t off = (size_t)(which * 8 + b) * 32768 +
                 (size_t)((r >> 5) * 4 + (c >> 4)) * 512 +
                 ((((r & 31) >> 3) * 16) + (c & 15)) * 8 + (r & 7);
    Wall_h[off] = h;
    Wall_l[off] = f2bf(x - bf2f(h));
  } else if (i < 786432 + 262144) {
    int rem = i - 786432;
    int c = rem >> 9, r = rem & 511;  // c: out col 0..511, r: k 0..511
    size_t off = (size_t)(c >> 6) * 32768 +
                 (size_t)((r >> 5) * 4 + ((c >> 4) & 3)) * 512 +
                 ((((r & 31) >> 3) * 16) + (c & 15)) * 8 + (r & 7);
    WoTp[off] = f2bf(Wo[r * 512 + c]);
  }
}

// ------------- fused projection GEMM (q,k,v in one launch) -------------
// grid (64, 24): y = which*8 + head. which 0: q (scale 1/8, split out),
// 1: k (split out), 2: v (plain out, transposed [h][d][n], key-axis sigma-permuted).
// 1-step register-prefetch pipeline; B loads are contiguous 1KB/wave fragments.
__global__ __launch_bounds__(256) void proj_gemm(const float* __restrict__ Q,
                                                 const float* __restrict__ Kin,
                                                 const float* __restrict__ Vin,
                                                 const u16* __restrict__ Wall_h,
                                                 const u16* __restrict__ Wall_l,
                                                 u16* __restrict__ qhh, u16* __restrict__ qhl,
                                                 u16* __restrict__ khh, u16* __restrict__ khl,
                                                 u16* __restrict__ vTp) {
  const int n = 4096, K = 512, N = 64;
  int rb = blockIdx.x;
  int which = blockIdx.y >> 3, b = blockIdx.y & 7;
  int wave = threadIdx.x >> 6, lane = threadIdx.x & 63;
  int lr = lane & 15, lg = lane >> 4;
  int row0 = rb * 64 + wave * 16;

  const float* A = which == 0 ? Q : which == 1 ? Kin : Vin;
  const u16* Bh = Wall_h + (size_t)(which * 8 + b) * 32768 + lane * 8;
  const u16* Bl = Wall_l + (size_t)(which * 8 + b) * 32768 + lane * 8;
  float scale = which == 0 ? 0.125f : 1.0f;

  const float* Arow = A + (size_t)(row0 + lr) * K + lg * 8;

  union U8 { unsigned w[4]; bf16x8 v; };
  f32x4 acc[4] = {};

  float4 a0 = *(const float4*)(Arow);
  float4 a1 = *(const float4*)(Arow + 4);
  bf16x8 bh[4], bl[4];
#pragma unroll
  for (int ct = 0; ct < 4; ++ct) {
    bh[ct] = *(const bf16x8*)(Bh + ct * 512);
    bl[ct] = *(const bf16x8*)(Bl + ct * 512);
  }

#pragma unroll
  for (int ks = 0; ks < 16; ++ks) {
    float4 a0n, a1n;
    bf16x8 bhn[4], bln[4];
    if (ks < 15) {  // issue next k-step's loads before computing this one
      a0n = *(const float4*)(Arow + (ks + 1) * 32);
      a1n = *(const float4*)(Arow + (ks + 1) * 32 + 4);
#pragma unroll
      for (int ct = 0; ct < 4; ++ct) {
        bhn[ct] = *(const bf16x8*)(Bh + ((ks + 1) * 4 + ct) * 512);
        bln[ct] = *(const bf16x8*)(Bl + ((ks + 1) * 4 + ct) * 512);
      }
    }
    U8 ah, al;
    split2(a0.x, a0.y, ah.w[0], al.w[0]);
    split2(a0.z, a0.w, ah.w[1], al.w[1]);
    split2(a1.x, a1.y, ah.w[2], al.w[2]);
    split2(a1.z, a1.w, ah.w[3], al.w[3]);
#pragma unroll
    for (int ct = 0; ct < 4; ++ct) {
      acc[ct] = __builtin_amdgcn_mfma_f32_16x16x32_bf16(ah.v, bh[ct], acc[ct], 0, 0, 0);
      acc[ct] = __builtin_amdgcn_mfma_f32_16x16x32_bf16(al.v, bh[ct], acc[ct], 0, 0, 0);
      acc[ct] = __builtin_amdgcn_mfma_f32_16x16x32_bf16(ah.v, bl[ct], acc[ct], 0, 0, 0);
    }
    if (ks < 15) {
      a0 = a0n; a1 = a1n;
#pragma unroll
      for (int ct = 0; ct < 4; ++ct) { bh[ct] = bhn[ct]; bl[ct] = bln[ct]; }
    }
  }

#pragma unroll
  for (int ct = 0; ct < 4; ++ct)
#pragma unroll
    for (int r = 0; r < 4; ++r) {
      float v = acc[ct][r] * scale;
      int row = row0 + lg * 4 + r;
      int col = ct * 16 + lr;
      if (which == 2) {
        int prow = (row & ~63) | sigma64(row & 63);
        vTp[((size_t)b * N + col) * n + prow] = f2bf(v);
      } else {
        size_t idx = ((size_t)b * n + row) * N + col;
        u16 hh = f2bf(v);
        if (which == 0) { qhh[idx] = hh; qhl[idx] = f2bf(v - bf2f(hh)); }
        else            { khh[idx] = hh; khl[idx] = f2bf(v - bf2f(hh)); }
      }
    }
}

// ---------------- flash attention (swapped QK^T, split-KV x2) ----------------
// unchanged from R5.
__global__ __launch_bounds__(256) void attn_kernel(const u16* __restrict__ qhh,
                                                   const u16* __restrict__ qhl,
                                                   const u16* __restrict__ khh,
                                                   const u16* __restrict__ khl,
                                                   const u16* __restrict__ vT,
                                                   u16* __restrict__ Opart,
                                                   float2* __restrict__ ml) {
  const int n = 4096, d = 64;
  int qb = blockIdx.x, h = blockIdx.y, half = blockIdx.z;
  int wave = threadIdx.x >> 6, lane = threadIdx.x & 63;
  int c = lane & 15, g = lane >> 4;
  int t = threadIdx.x;

  __shared__ u16 KH[64 * 64];
  __shared__ u16 KL[64 * 64];
  __shared__ u16 VS[64 * 64];
  char* KHb = (char*)KH;
  char* KLb = (char*)KL;
  char* VSb = (char*)VS;

  int qrow0 = qb * 64 + wave * 16;
  bf16x8 qfh[2], qfl[2];
#pragma unroll
  for (int ks = 0; ks < 2; ++ks) {
    size_t qoff = ((size_t)h * n + qrow0 + c) * d + ks * 32 + g * 8;
    qfh[ks] = *(const bf16x8*)(qhh + qoff);
    qfl[ks] = *(const bf16x8*)(qhl + qoff);
  }

  f32x4 accO[4] = {};
  float m = -INFINITY, l = 0.f;

  int rr = t >> 3, cb8 = (t & 7) * 8, cw = (t & 7) * 16;
  const u16* kA = khh + ((size_t)h * n + half * 2048 + rr) * d + cb8;
  const u16* lA = khl + ((size_t)h * n + half * 2048 + rr) * d + cb8;
  const u16* vA = vT + (size_t)h * d * n + (size_t)rr * n + half * 2048 + cb8;

  bf16x8 p0, p1, p2, p3, p4, p5;
#define ISSUE(kv0)                                            \
  do {                                                        \
    size_t ko = (size_t)(kv0) * d;                            \
    p0 = *(const bf16x8*)(kA + ko);                           \
    p1 = *(const bf16x8*)(kA + ko + 32 * d);                  \
    p2 = *(const bf16x8*)(lA + ko);                           \
    p3 = *(const bf16x8*)(lA + ko + 32 * d);                  \
    p4 = *(const bf16x8*)(vA + (kv0));                        \
    p5 = *(const bf16x8*)(vA + (kv0) + 32 * n);               \
  } while (0)

  ISSUE(0);
  for (int it = 0; it < 32; ++it) {
    *(bf16x8*)(KHb + SWZ(rr, cw)) = p0;
    *(bf16x8*)(KHb + SWZ(rr + 32, cw)) = p1;
    *(bf16x8*)(KLb + SWZ(rr, cw)) = p2;
    *(bf16x8*)(KLb + SWZ(rr + 32, cw)) = p3;
    *(bf16x8*)(VSb + SWZ(rr, cw)) = p4;
    *(bf16x8*)(VSb + SWZ(rr + 32, cw)) = p5;
    __syncthreads();
    if (it < 31) ISSUE((it + 1) * 64);

    f32x4 s[4] = {};
#pragma unroll
    for (int ct = 0; ct < 4; ++ct) {
      int R = ct * 16 + c;
#pragma unroll
      for (int ks = 0; ks < 2; ++ks) {
        bf16x8 kh_f = *(const bf16x8*)(KHb + SWZ(R, ks * 64 + g * 16));
        s[ct] = __builtin_amdgcn_mfma_f32_16x16x32_bf16(kh_f, qfh[ks], s[ct], 0, 0, 0);
        s[ct] = __builtin_amdgcn_mfma_f32_16x16x32_bf16(kh_f, qfl[ks], s[ct], 0, 0, 0);
        bf16x8 kl_f = *(const bf16x8*)(KLb + SWZ(R, ks * 64 + g * 16));
        s[ct] = __builtin_amdgcn_mfma_f32_16x16x32_bf16(kl_f, qfh[ks], s[ct], 0, 0, 0);
      }
    }

    float mx0 = fmaxf(fmaxf(s[0][0], s[0][1]), fmaxf(s[0][2], s[0][3]));
    float mx1 = fmaxf(fmaxf(s[1][0], s[1][1]), fmaxf(s[1][2], s[1][3]));
    float mx2 = fmaxf(fmaxf(s[2][0], s[2][1]), fmaxf(s[2][2], s[2][3]));
    float mx3 = fmaxf(fmaxf(s[3][0], s[3][1]), fmaxf(s[3][2], s[3][3]));
    float mx = fmaxf(fmaxf(mx0, mx1), fmaxf(mx2, mx3));
    mx = fmaxf(mx, __shfl_xor(mx, 16));
    mx = fmaxf(mx, __shfl_xor(mx, 32));
    bool need = mx > m;
    float mn = need ? mx : m;
    float rs = 0.f;
#pragma unroll
    for (int ct = 0; ct < 4; ++ct) {
      float q0 = __expf(s[ct][0] - mn);
      float q1 = __expf(s[ct][1] - mn);
      float q2 = __expf(s[ct][2] - mn);
      float q3 = __expf(s[ct][3] - mn);
      s[ct][0] = q0; s[ct][1] = q1; s[ct][2] = q2; s[ct][3] = q3;
      rs += (q0 + q1) + (q2 + q3);
    }
    rs += __shfl_xor(rs, 16);
    rs += __shfl_xor(rs, 32);

    if (__any(need)) {
      float alpha = __expf(m - mn);
      m = mn;
      l = l * alpha + rs;
#pragma unroll
      for (int r = 0; r < 4; ++r) {
        float ar = __shfl(alpha, g * 4 + r);
#pragma unroll
        for (int dt = 0; dt < 4; ++dt) accO[dt][r] *= ar;
      }
    } else {
      l += rs;
    }

    union { unsigned w[4]; bf16x8 v; } pa[2];
#pragma unroll
    for (int ks = 0; ks < 2; ++ks) {
      pa[ks].w[0] = cvt_pk_bf16(s[ks][0], s[ks][1]);
      pa[ks].w[1] = cvt_pk_bf16(s[ks][2], s[ks][3]);
      pa[ks].w[2] = cvt_pk_bf16(s[ks + 2][0], s[ks + 2][1]);
      pa[ks].w[3] = cvt_pk_bf16(s[ks + 2][2], s[ks + 2][3]);
    }

#pragma unroll
    for (int dt = 0; dt < 4; ++dt) {
      int R = dt * 16 + c;
#pragma unroll
      for (int ks = 0; ks < 2; ++ks) {
        bf16x8 vf = *(const bf16x8*)(VSb + SWZ(R, ks * 64 + g * 16));
        accO[dt] = __builtin_amdgcn_mfma_f32_16x16x32_bf16(pa[ks].v, vf, accO[dt], 0, 0, 0);
      }
    }
    __syncthreads();
  }
#undef ISSUE

  u16* Ob = Opart + (((size_t)half * 8 + h) * n) * d;
  float2* mlp = ml + ((size_t)half * 8 + h) * n;
#pragma unroll
  for (int r = 0; r < 4; ++r) {
    int row = qrow0 + g * 4 + r;
#pragma unroll
    for (int dt = 0; dt < 4; ++dt)
      Ob[(size_t)row * d + dt * 16 + c] = f2bf(accO[dt][r]);
  }
  if (g == 0) mlp[qrow0 + c] = make_float2(m, l);
}

// ---------------- combine the two KV halves ----------------
__global__ __launch_bounds__(256) void attn_combine(const u16* __restrict__ Opart,
                                                    const float2* __restrict__ ml,
                                                    u16* __restrict__ att) {
  int tid = blockIdx.x * 256 + threadIdx.x;
  int chunk = tid & 7;
  int h = (tid >> 3) & 7;
  int row = tid >> 6;
  float2 ml0 = ml[(size_t)h * 4096 + row];
  float2 ml1 = ml[(size_t)(8 + h) * 4096 + row];
  float mstar = fmaxf(ml0.x, ml1.x);
  float w0 = __expf(ml0.x - mstar), w1 = __expf(ml1.x - mstar);
  float inv = 1.f / (ml0.y * w0 + ml1.y * w1);
  w0 *= inv; w1 *= inv;
  bf16x8 o0 = *(const bf16x8*)(Opart + ((size_t)h * 4096 + row) * 64 + chunk * 8);
  bf16x8 o1 = *(const bf16x8*)(Opart + ((size_t)(8 + h) * 4096 + row) * 64 + chunk * 8);
  bf16x8 res;
#pragma unroll
  for (int j = 0; j < 8; ++j)
    res[j] = (short)f2bf(bf2f((u16)o0[j]) * w0 + bf2f((u16)o1[j]) * w1);
  *(bf16x8*)(att + (size_t)row * 512 + h * 64 + chunk * 8) = res;
}

// ------- final projection: out = att @ Wo (fp32 out), fragment-packed B -------
__global__ __launch_bounds__(256) void final_gemm(const u16* __restrict__ A,
                                                  const u16* __restrict__ BTp,
                                                  float* __restrict__ out,
                                                  int M, int K, int N) {
  int rb = blockIdx.x, cb = blockIdx.y;
  int wave = threadIdx.x >> 6, lane = threadIdx.x & 63;
  int lr = lane & 15, lg = lane >> 4;
  int row0 = rb * 64 + wave * 16;

  const u16* Arow = A + (size_t)(row0 + lr) * K + lg * 8;
  const u16* Bp = BTp + (size_t)cb * 32768 + lane * 8;

  f32x4 acc[4] = {};
  bf16x8 a = *(const bf16x8*)(Arow);
  bf16x8 bfr[4];
#pragma unroll
  for (int ct = 0; ct < 4; ++ct) bfr[ct] = *(const bf16x8*)(Bp + ct * 512);

#pragma unroll
  for (int ks = 0; ks < 16; ++ks) {
    bf16x8 an, bfn[4];
    if (ks < 15) {
      an = *(const bf16x8*)(Arow + (ks + 1) * 32);
#pragma unroll
      for (int ct = 0; ct < 4; ++ct)
        bfn[ct] = *(const bf16x8*)(Bp + ((ks + 1) * 4 + ct) * 512);
    }
#pragma unroll
    for (int ct = 0; ct < 4; ++ct)
      acc[ct] = __builtin_amdgcn_mfma_f32_16x16x32_bf16(a, bfr[ct], acc[ct], 0, 0, 0);
    if (ks < 15) {
      a = an;
#pragma unroll
      for (int ct = 0; ct < 4; ++ct) bfr[ct] = bfn[ct];
    }
  }
#pragma unroll
  for (int ct = 0; ct < 4; ++ct)
#pragma unroll
    for (int r = 0; r < 4; ++r)
      out[(size_t)(row0 + lg * 4 + r) * N + cb * 64 + ct * 16 + lr] = acc[ct][r];
}

// ---------------- launch ----------------
extern "C" void kernel_launch(void* const* d_in, const int* in_sizes, int n_in,
                              void* d_out, int out_size, void* d_ws, size_t ws_size,
                              hipStream_t stream) {
  const float* Q = (const float*)d_in[0];
  const float* K = (const float*)d_in[1];
  const float* V = (const float*)d_in[2];
  const float* Wq = (const float*)d_in[3];
  const float* Wk = (const float*)d_in[4];
  const float* Wv = (const float*)d_in[5];
  const float* Wo = (const float*)d_in[6];
  float* out = (float*)d_out;

  const int n = 4096, dim = 512;
  const size_t KB = 1 << 10, MB = 1 << 20;
  char* ws = (char*)d_ws;
  u16* qhh    = (u16*)(ws + 0 * MB);   // 4 MB each
  u16* qhl    = (u16*)(ws + 4 * MB);
  u16* khh    = (u16*)(ws + 8 * MB);
  u16* khl    = (u16*)(ws + 12 * MB);
  u16* vTp    = (u16*)(ws + 16 * MB);
  u16* Wall_h = (u16*)(ws + 20 * MB);              // 1.5 MB
  u16* Wall_l = (u16*)(ws + 20 * MB + 1536 * KB);  // 1.5 MB
  u16* WoTp   = (u16*)(ws + 23 * MB);              // 512 KB
  float2* ml  = (float2*)(ws + 23 * MB + 512 * KB);  // 512 KB
  u16* Opart  = (u16*)(ws + 24 * MB);              // 8 MB -> ends at 32 MB
  u16* att    = qhh;  // reused after attn

  prep_weights<<<4096, 256, 0, stream>>>(Wq, Wk, Wv, Wo, Wall_h, Wall_l, WoTp);

  proj_gemm<<<dim3(n / 64, 24), 256, 0, stream>>>(Q, K, V, Wall_h, Wall_l,
                                                  qhh, qhl, khh, khl, vTp);

  attn_kernel<<<dim3(n / 64, 8, 2), 256, 0, stream>>>(qhh, qhl, khh, khl, vTp, Opart, ml);
  attn_combine<<<(n * 8 * 8) / 256, 256, 0, stream>>>(Opart, ml, att);

  final_gemm<<<dim3(n / 64, dim / 64), 256, 0, stream>>>(att, WoTp, out, n, dim, dim);
}

// Round 7
// 168.223 us; speedup vs baseline: 2.4795x; 1.0551x over previous
//
#include <hip/hip_runtime.h>

// MultiHeadAttentionLayer: n=4096, dim=512, h=8, d=64, fp32 in/out.
// bf16 MFMA + Dekker split upstream of softmax. R7: attn reworked for the
// LDS-bandwidth wall: 32 q-rows/wave (halves per-q LDS reads), global_load_lds
// staging from pre-swizzled global K/V chunks (no ds_writes, no prefetch VGPRs),
// KH/VS double-buffer + KL single-buffer with counted-wait schedule.

typedef __attribute__((ext_vector_type(8))) short bf16x8;
typedef __attribute__((ext_vector_type(4))) float f32x4;
typedef unsigned short u16;

static __device__ __forceinline__ u16 f2bf(float f) {
  union { float f; unsigned u; } v; v.f = f;
  unsigned r = v.u + 0x7fffu + ((v.u >> 16) & 1u);
  return (u16)(r >> 16);
}
static __device__ __forceinline__ float bf2f(u16 h) {
  union { unsigned u; float f; } v; v.u = ((unsigned)h) << 16; return v.f;
}
static __device__ __forceinline__ unsigned cvt_pk_bf16(float lo, float hi) {
  unsigned r;
  asm("v_cvt_pk_bf16_f32 %0, %1, %2" : "=v"(r) : "v"(lo), "v"(hi));
  return r;
}
static __device__ __forceinline__ void split2(float v0, float v1,
                                              unsigned& hw, unsigned& lw) {
  unsigned h = cvt_pk_bf16(v0, v1);
  float h0 = __uint_as_float(h << 16);
  float h1 = __uint_as_float(h & 0xffff0000u);
  hw = h;
  lw = cvt_pk_bf16(v0 - h0, v1 - h1);
}

// byte address of (row, byteoff) in a row-stride-128B tile image, XOR-swizzled.
#define SWZ(row, byteoff) ((((row) * 128) + (byteoff)) ^ (((row) & 7) << 4))

// sigma: key -> storage col within a 64-block so PV fragment (ks,g) reads keys
// kappa(ks,g,j)=16(ks+2(j>>2))+4g+(j&3) as contiguous cols 32ks+8g+j.
static __device__ __forceinline__ int sigma64(int k) {
  return (k & 3) | (((k >> 5) & 1) << 2) | (((k >> 2) & 3) << 3) | (((k >> 4) & 1) << 5);
}

#define GLOAD16(gp, lp)                                              \
  __builtin_amdgcn_global_load_lds(                                  \
      (const __attribute__((address_space(1))) void*)(gp),           \
      (__attribute__((address_space(3))) void*)(lp), 16, 0, 0)

// ---------------- weight prep (fragment-packed, unchanged from R6) ----------------
__global__ __launch_bounds__(256) void prep_weights(const float* __restrict__ Wq,
                                                    const float* __restrict__ Wk,
                                                    const float* __restrict__ Wv,
                                                    const float* __restrict__ Wo,
                                                    u16* __restrict__ Wall_h,
                                                    u16* __restrict__ Wall_l,
                                                    u16* __restrict__ WoTp) {
  int i = blockIdx.x * 256 + threadIdx.x;
  if (i < 786432) {
    int which = i / 262144, rem = i - which * 262144;
    int b = rem >> 15, r2 = rem & 32767;
    int c = r2 >> 9, r = r2 & 511;
    const float* W = which == 0 ? Wq : which == 1 ? Wk : Wv;
    float x = W[(b << 15) + r * 64 + c];
    u16 h = f2bf(x);
    size_t off = (size_t)(which * 8 + b) * 32768 +
                 (size_t)((r >> 5) * 4 + (c >> 4)) * 512 +
                 ((((r & 31) >> 3) * 16) + (c & 15)) * 8 + (r & 7);
    Wall_h[off] = h;
    Wall_l[off] = f2bf(x - bf2f(h));
  } else if (i < 786432 + 262144) {
    int rem = i - 786432;
    int c = rem >> 9, r = rem & 511;
    size_t off = (size_t)(c >> 6) * 32768 +
                 (size_t)((r >> 5) * 4 + ((c >> 4) & 3)) * 512 +
                 ((((r & 31) >> 3) * 16) + (c & 15)) * 8 + (r & 7);
    WoTp[off] = f2bf(Wo[r * 512 + c]);
  }
}

// ------------- fused projection GEMM -------------
// which 0: q split [h][n][64] (scale 1/8). which 1: k split -> swizzled 8KB
// tile chunks (LDS image). which 2: v -> swizzled sigma-permuted chunks.
__global__ __launch_bounds__(256) void proj_gemm(const float* __restrict__ Q,
                                                 const float* __restrict__ Kin,
                                                 const float* __restrict__ Vin,
                                                 const u16* __restrict__ Wall_h,
                                                 const u16* __restrict__ Wall_l,
                                                 u16* __restrict__ qhh, u16* __restrict__ qhl,
                                                 u16* __restrict__ khg, u16* __restrict__ klg,
                                                 u16* __restrict__ vsg) {
  const int n = 4096, K = 512, N = 64;
  int rb = blockIdx.x;
  int which = blockIdx.y >> 3, b = blockIdx.y & 7;
  int wave = threadIdx.x >> 6, lane = threadIdx.x & 63;
  int lr = lane & 15, lg = lane >> 4;
  int row0 = rb * 64 + wave * 16;

  const float* A = which == 0 ? Q : which == 1 ? Kin : Vin;
  const u16* Bh = Wall_h + (size_t)(which * 8 + b) * 32768 + lane * 8;
  const u16* Bl = Wall_l + (size_t)(which * 8 + b) * 32768 + lane * 8;
  float scale = which == 0 ? 0.125f : 1.0f;

  const float* Arow = A + (size_t)(row0 + lr) * K + lg * 8;

  union U8 { unsigned w[4]; bf16x8 v; };
  f32x4 acc[4] = {};

  float4 a0 = *(const float4*)(Arow);
  float4 a1 = *(const float4*)(Arow + 4);
  bf16x8 bh[4], bl[4];
#pragma unroll
  for (int ct = 0; ct < 4; ++ct) {
    bh[ct] = *(const bf16x8*)(Bh + ct * 512);
    bl[ct] = *(const bf16x8*)(Bl + ct * 512);
  }

#pragma unroll
  for (int ks = 0; ks < 16; ++ks) {
    float4 a0n, a1n;
    bf16x8 bhn[4], bln[4];
    if (ks < 15) {
      a0n = *(const float4*)(Arow + (ks + 1) * 32);
      a1n = *(const float4*)(Arow + (ks + 1) * 32 + 4);
#pragma unroll
      for (int ct = 0; ct < 4; ++ct) {
        bhn[ct] = *(const bf16x8*)(Bh + ((ks + 1) * 4 + ct) * 512);
        bln[ct] = *(const bf16x8*)(Bl + ((ks + 1) * 4 + ct) * 512);
      }
    }
    U8 ah, al;
    split2(a0.x, a0.y, ah.w[0], al.w[0]);
    split2(a0.z, a0.w, ah.w[1], al.w[1]);
    split2(a1.x, a1.y, ah.w[2], al.w[2]);
    split2(a1.z, a1.w, ah.w[3], al.w[3]);
#pragma unroll
    for (int ct = 0; ct < 4; ++ct) {
      acc[ct] = __builtin_amdgcn_mfma_f32_16x16x32_bf16(ah.v, bh[ct], acc[ct], 0, 0, 0);
      acc[ct] = __builtin_amdgcn_mfma_f32_16x16x32_bf16(al.v, bh[ct], acc[ct], 0, 0, 0);
      acc[ct] = __builtin_amdgcn_mfma_f32_16x16x32_bf16(ah.v, bl[ct], acc[ct], 0, 0, 0);
    }
    if (ks < 15) {
      a0 = a0n; a1 = a1n;
#pragma unroll
      for (int ct = 0; ct < 4; ++ct) { bh[ct] = bhn[ct]; bl[ct] = bln[ct]; }
    }
  }

#pragma unroll
  for (int ct = 0; ct < 4; ++ct)
#pragma unroll
    for (int r = 0; r < 4; ++r) {
      float v = acc[ct][r] * scale;
      int row = row0 + lg * 4 + r;
      int col = ct * 16 + lr;
      if (which == 2) {
        size_t byte = ((size_t)b * 64 + (row >> 6)) * 8192 +
                      SWZ(col, 2 * sigma64(row & 63));
        *(u16*)((char*)vsg + byte) = f2bf(v);
      } else if (which == 1) {
        size_t byte = ((size_t)b * 64 + (row >> 6)) * 8192 + SWZ(row & 63, col * 2);
        u16 hh = f2bf(v);
        *(u16*)((char*)khg + byte) = hh;
        *(u16*)((char*)klg + byte) = f2bf(v - bf2f(hh));
      } else {
        size_t idx = ((size_t)b * n + row) * N + col;
        u16 hh = f2bf(v);
        qhh[idx] = hh;
        qhl[idx] = f2bf(v - bf2f(hh));
      }
    }
}

// ---------------- flash attention: 4 waves x 32 q-rows, split-KV x2 ----------------
// khg/klg/vsg: per (h, 64-key tile) 8KB pre-swizzled LDS images.
// Opart: [2][8][4096][64] bf16 unnormalized; ml: [2][8][4096] float2 (m, l)
__global__ __launch_bounds__(256) void attn_kernel(const u16* __restrict__ qhh,
                                                   const u16* __restrict__ qhl,
                                                   const u16* __restrict__ khg,
                                                   const u16* __restrict__ klg,
                                                   const u16* __restrict__ vsg,
                                                   u16* __restrict__ Opart,
                                                   float2* __restrict__ ml) {
  const int n = 4096, d = 64;
  int qb = blockIdx.x, h = blockIdx.y, part = blockIdx.z;
  int wave = threadIdx.x >> 6, lane = threadIdx.x & 63;
  int c = lane & 15, g = lane >> 4;

  __shared__ char SB[40960];  // [KH0 8K][KH1 8K][VS0 8K][VS1 8K][KL 8K]

  int qrow0 = qb * 128 + wave * 32;
  bf16x8 qfh[2][2], qfl[2][2];
#pragma unroll
  for (int b2 = 0; b2 < 2; ++b2)
#pragma unroll
    for (int ks = 0; ks < 2; ++ks) {
      size_t qoff = ((size_t)h * n + qrow0 + b2 * 16 + c) * d + ks * 32 + g * 8;
      qfh[b2][ks] = *(const bf16x8*)(qhh + qoff);
      qfl[b2][ks] = *(const bf16x8*)(qhl + qoff);
    }

  f32x4 accO[2][4] = {};
  float m[2] = {-INFINITY, -INFINITY}, l[2] = {0.f, 0.f};

  const char* khB = (const char*)khg + ((size_t)h * 64 + part * 32) * 8192;
  const char* klB = (const char*)klg + ((size_t)h * 64 + part * 32) * 8192;
  const char* vsB = (const char*)vsg + ((size_t)h * 64 + part * 32) * 8192;
  int so = wave * 2048;       // wave-uniform LDS slice
  int sg = so + lane * 16;    // per-lane global offset

#define STAGE_A(tile, buf)                                          \
  do {                                                              \
    const char* kg_ = khB + (size_t)(tile) * 8192 + sg;             \
    const char* vg_ = vsB + (size_t)(tile) * 8192 + sg;             \
    char* kd_ = SB + (buf) * 8192 + so;                             \
    char* vd_ = SB + 16384 + (buf) * 8192 + so;                     \
    GLOAD16(kg_, kd_);                                              \
    GLOAD16(kg_ + 1024, kd_ + 1024);                                \
    GLOAD16(vg_, vd_);                                              \
    GLOAD16(vg_ + 1024, vd_ + 1024);                                \
  } while (0)
#define STAGE_B(tile)                                               \
  do {                                                              \
    const char* lg_ = klB + (size_t)(tile) * 8192 + sg;             \
    char* ld_ = SB + 32768 + so;                                    \
    GLOAD16(lg_, ld_);                                              \
    GLOAD16(lg_ + 1024, ld_ + 1024);                                \
  } while (0)

  STAGE_A(0, 0);
  STAGE_B(0);

  for (int it = 0; it < 32; ++it) {
    int cur = it & 1;
    int nxt = it < 31 ? it + 1 : 31;  // clamp: last iter re-stages tile 31 (unused)
    asm volatile("s_waitcnt vmcnt(0)" ::: "memory");  // tile it landed (mine)
    __builtin_amdgcn_s_barrier();                     // all waves' tile landed; prev PV done
    STAGE_A(nxt, cur ^ 1);  // prefetch next KH/VS; latency hides under QK+softmax+PV

    const char* KHb = SB + cur * 8192;
    const char* KLb = SB + 32768;
    const char* VSb = SB + 16384 + cur * 8192;

    union { unsigned w[4]; bf16x8 v; } pa[2][2];
#pragma unroll
    for (int b2 = 0; b2 < 2; ++b2) {
      // S^T = K @ Q^T: s[ct] reg r = P~[key=ct*16+g*4+r][q=b2*16+c]
      f32x4 s[4] = {};
#pragma unroll
      for (int ct = 0; ct < 4; ++ct) {
        int R = ct * 16 + c;
#pragma unroll
        for (int ks = 0; ks < 2; ++ks) {
          bf16x8 kh_f = *(const bf16x8*)(KHb + SWZ(R, ks * 64 + g * 16));
          s[ct] = __builtin_amdgcn_mfma_f32_16x16x32_bf16(kh_f, qfh[b2][ks], s[ct], 0, 0, 0);
          s[ct] = __builtin_amdgcn_mfma_f32_16x16x32_bf16(kh_f, qfl[b2][ks], s[ct], 0, 0, 0);
          bf16x8 kl_f = *(const bf16x8*)(KLb + SWZ(R, ks * 64 + g * 16));
          s[ct] = __builtin_amdgcn_mfma_f32_16x16x32_bf16(kl_f, qfh[b2][ks], s[ct], 0, 0, 0);
        }
      }

      // in-register online softmax for q-row (b2*16 + c)
      float mx0 = fmaxf(fmaxf(s[0][0], s[0][1]), fmaxf(s[0][2], s[0][3]));
      float mx1 = fmaxf(fmaxf(s[1][0], s[1][1]), fmaxf(s[1][2], s[1][3]));
      float mx2 = fmaxf(fmaxf(s[2][0], s[2][1]), fmaxf(s[2][2], s[2][3]));
      float mx3 = fmaxf(fmaxf(s[3][0], s[3][1]), fmaxf(s[3][2], s[3][3]));
      float mx = fmaxf(fmaxf(mx0, mx1), fmaxf(mx2, mx3));
      mx = fmaxf(mx, __shfl_xor(mx, 16));
      mx = fmaxf(mx, __shfl_xor(mx, 32));
      bool need = mx > m[b2];
      float mn = need ? mx : m[b2];
      float rs = 0.f;
#pragma unroll
      for (int ct = 0; ct < 4; ++ct) {
        float q0 = __expf(s[ct][0] - mn);
        float q1 = __expf(s[ct][1] - mn);
        float q2 = __expf(s[ct][2] - mn);
        float q3 = __expf(s[ct][3] - mn);
        s[ct][0] = q0; s[ct][1] = q1; s[ct][2] = q2; s[ct][3] = q3;
        rs += (q0 + q1) + (q2 + q3);
      }
      rs += __shfl_xor(rs, 16);
      rs += __shfl_xor(rs, 32);

      if (__any(need)) {  // exact defer-rescale
        float alpha = __expf(m[b2] - mn);
        m[b2] = mn;
        l[b2] = l[b2] * alpha + rs;
#pragma unroll
        for (int r = 0; r < 4; ++r) {
          float ar = __shfl(alpha, g * 4 + r);
#pragma unroll
          for (int dt = 0; dt < 4; ++dt) accO[b2][dt][r] *= ar;
        }
      } else {
        l[b2] += rs;
      }

      // pack P in-lane: PV HW slot (ks; g, j) holds key 16(ks+2(j>>2))+4g+(j&3)
#pragma unroll
      for (int ks = 0; ks < 2; ++ks) {
        pa[b2][ks].w[0] = cvt_pk_bf16(s[ks][0], s[ks][1]);
        pa[b2][ks].w[1] = cvt_pk_bf16(s[ks][2], s[ks][3]);
        pa[b2][ks].w[2] = cvt_pk_bf16(s[ks + 2][0], s[ks + 2][1]);
        pa[b2][ks].w[3] = cvt_pk_bf16(s[ks + 2][2], s[ks + 2][3]);
      }
    }

    __builtin_amdgcn_s_barrier();  // all waves done reading KL
    STAGE_B(nxt);                  // prefetch next KL; latency hides under PV

    // O += P @ V: V fragments shared across both q-blocks (read once)
#pragma unroll
    for (int dt = 0; dt < 4; ++dt) {
      int R = dt * 16 + c;
#pragma unroll
      for (int ks = 0; ks < 2; ++ks) {
        bf16x8 vf = *(const bf16x8*)(VSb + SWZ(R, ks * 64 + g * 16));
        accO[0][dt] = __builtin_amdgcn_mfma_f32_16x16x32_bf16(pa[0][ks].v, vf, accO[0][dt], 0, 0, 0);
        accO[1][dt] = __builtin_amdgcn_mfma_f32_16x16x32_bf16(pa[1][ks].v, vf, accO[1][dt], 0, 0, 0);
      }
    }
  }
#undef STAGE_A
#undef STAGE_B

  // epilogue: unnormalized O + (m,l)
  u16* Ob = Opart + (((size_t)part * 8 + h) * n) * d;
  float2* mlp = ml + ((size_t)part * 8 + h) * n;
#pragma unroll
  for (int b2 = 0; b2 < 2; ++b2) {
#pragma unroll
    for (int r = 0; r < 4; ++r) {
      int row = qrow0 + b2 * 16 + g * 4 + r;
#pragma unroll
      for (int dt = 0; dt < 4; ++dt)
        Ob[(size_t)row * d + dt * 16 + c] = f2bf(accO[b2][dt][r]);
    }
    if (g == 0) mlp[qrow0 + b2 * 16 + c] = make_float2(m[b2], l[b2]);
  }
}

// ---------------- combine the two KV halves ----------------
__global__ __launch_bounds__(256) void attn_combine(const u16* __restrict__ Opart,
                                                    const float2* __restrict__ ml,
                                                    u16* __restrict__ att) {
  int tid = blockIdx.x * 256 + threadIdx.x;
  int chunk = tid & 7;
  int h = (tid >> 3) & 7;
  int row = tid >> 6;
  float2 ml0 = ml[(size_t)h * 4096 + row];
  float2 ml1 = ml[(size_t)(8 + h) * 4096 + row];
  float mstar = fmaxf(ml0.x, ml1.x);
  float w0 = __expf(ml0.x - mstar), w1 = __expf(ml1.x - mstar);
  float inv = 1.f / (ml0.y * w0 + ml1.y * w1);
  w0 *= inv; w1 *= inv;
  bf16x8 o0 = *(const bf16x8*)(Opart + ((size_t)h * 4096 + row) * 64 + chunk * 8);
  bf16x8 o1 = *(const bf16x8*)(Opart + ((size_t)(8 + h) * 4096 + row) * 64 + chunk * 8);
  bf16x8 res;
#pragma unroll
  for (int j = 0; j < 8; ++j)
    res[j] = (short)f2bf(bf2f((u16)o0[j]) * w0 + bf2f((u16)o1[j]) * w1);
  *(bf16x8*)(att + (size_t)row * 512 + h * 64 + chunk * 8) = res;
}

// ------- final projection: out = att @ Wo (fp32 out), fragment-packed B -------
__global__ __launch_bounds__(256) void final_gemm(const u16* __restrict__ A,
                                                  const u16* __restrict__ BTp,
                                                  float* __restrict__ out,
                                                  int M, int K, int N) {
  int rb = blockIdx.x, cb = blockIdx.y;
  int wave = threadIdx.x >> 6, lane = threadIdx.x & 63;
  int lr = lane & 15, lg = lane >> 4;
  int row0 = rb * 64 + wave * 16;

  const u16* Arow = A + (size_t)(row0 + lr) * K + lg * 8;
  const u16* Bp = BTp + (size_t)cb * 32768 + lane * 8;

  f32x4 acc[4] = {};
  bf16x8 a = *(const bf16x8*)(Arow);
  bf16x8 bfr[4];
#pragma unroll
  for (int ct = 0; ct < 4; ++ct) bfr[ct] = *(const bf16x8*)(Bp + ct * 512);

#pragma unroll
  for (int ks = 0; ks < 16; ++ks) {
    bf16x8 an, bfn[4];
    if (ks < 15) {
      an = *(const bf16x8*)(Arow + (ks + 1) * 32);
#pragma unroll
      for (int ct = 0; ct < 4; ++ct)
        bfn[ct] = *(const bf16x8*)(Bp + ((ks + 1) * 4 + ct) * 512);
    }
#pragma unroll
    for (int ct = 0; ct < 4; ++ct)
      acc[ct] = __builtin_amdgcn_mfma_f32_16x16x32_bf16(a, bfr[ct], acc[ct], 0, 0, 0);
    if (ks < 15) {
      a = an;
#pragma unroll
      for (int ct = 0; ct < 4; ++ct) bfr[ct] = bfn[ct];
    }
  }
#pragma unroll
  for (int ct = 0; ct < 4; ++ct)
#pragma unroll
    for (int r = 0; r < 4; ++r)
      out[(size_t)(row0 + lg * 4 + r) * N + cb * 64 + ct * 16 + lr] = acc[ct][r];
}

// ---------------- launch ----------------
extern "C" void kernel_launch(void* const* d_in, const int* in_sizes, int n_in,
                              void* d_out, int out_size, void* d_ws, size_t ws_size,
                              hipStream_t stream) {
  const float* Q = (const float*)d_in[0];
  const float* K = (const float*)d_in[1];
  const float* V = (const float*)d_in[2];
  const float* Wq = (const float*)d_in[3];
  const float* Wk = (const float*)d_in[4];
  const float* Wv = (const float*)d_in[5];
  const float* Wo = (const float*)d_in[6];
  float* out = (float*)d_out;

  const int n = 4096, dim = 512;
  const size_t KB = 1 << 10, MB = 1 << 20;
  char* ws = (char*)d_ws;
  u16* qhh    = (u16*)(ws + 0 * MB);   // 4 MB each
  u16* qhl    = (u16*)(ws + 4 * MB);
  u16* khg    = (u16*)(ws + 8 * MB);   // swizzled K-hi tile chunks
  u16* klg    = (u16*)(ws + 12 * MB);  // swizzled K-lo tile chunks
  u16* vsg    = (u16*)(ws + 16 * MB);  // swizzled sigma-permuted V chunks
  u16* Opart  = (u16*)(ws + 20 * MB);  // 8 MB (2 parts)
  float2* ml  = (float2*)(ws + 28 * MB);            // 512 KB
  u16* WoTp   = (u16*)(ws + 28 * MB + 512 * KB);    // 512 KB
  u16* Wall_h = (u16*)(ws + 29 * MB);               // 1.5 MB
  u16* Wall_l = (u16*)(ws + 29 * MB + 1536 * KB);   // 1.5 MB -> ends at 32 MB
  u16* att    = khg;  // khg dead after attn; combine writes att here

  prep_weights<<<4096, 256, 0, stream>>>(Wq, Wk, Wv, Wo, Wall_h, Wall_l, WoTp);

  proj_gemm<<<dim3(n / 64, 24), 256, 0, stream>>>(Q, K, V, Wall_h, Wall_l,
                                                  qhh, qhl, khg, klg, vsg);

  attn_kernel<<<dim3(32, 8, 2), 256, 0, stream>>>(qhh, qhl, khg, klg, vsg, Opart, ml);
  attn_combine<<<(n * 8 * 8) / 256, 256, 0, stream>>>(Opart, ml, att);

  final_gemm<<<dim3(n / 64, dim / 64), 256, 0, stream>>>(att, WoTp, out, n, dim, dim);
}

// Round 8
// 131.943 us; speedup vs baseline: 3.1613x; 1.2750x over previous
//
#include <hip/hip_runtime.h>

// MultiHeadAttentionLayer: n=4096, dim=512, h=8, d=64, fp32 in/out.
// R8: q,k stored fp16 (2^-12 rel err -> score err ~0.04, replaces the Dekker
// x3 bf16 QK^T with a single mfma_f32_16x16x32_f16) -- QK MFMA x3 -> x1, KL
// buffer deleted. Split-KV x4 (grid 1024 = 4 blocks/CU). Projections keep
// Dekker bf16 internally for accuracy; PV stays bf16.

typedef __attribute__((ext_vector_type(8))) short bf16x8;
typedef __attribute__((ext_vector_type(8))) _Float16 f16x8;
typedef __attribute__((ext_vector_type(4))) float f32x4;
typedef unsigned short u16;

static __device__ __forceinline__ u16 f2bf(float f) {
  union { float f; unsigned u; } v; v.f = f;
  unsigned r = v.u + 0x7fffu + ((v.u >> 16) & 1u);
  return (u16)(r >> 16);
}
static __device__ __forceinline__ float bf2f(u16 h) {
  union { unsigned u; float f; } v; v.u = ((unsigned)h) << 16; return v.f;
}
static __device__ __forceinline__ u16 f2h(float f) {
  union { _Float16 h; u16 u; } v; v.h = (_Float16)f; return v.u;
}
static __device__ __forceinline__ unsigned cvt_pk_bf16(float lo, float hi) {
  unsigned r;
  asm("v_cvt_pk_bf16_f32 %0, %1, %2" : "=v"(r) : "v"(lo), "v"(hi));
  return r;
}
static __device__ __forceinline__ void split2(float v0, float v1,
                                              unsigned& hw, unsigned& lw) {
  unsigned h = cvt_pk_bf16(v0, v1);
  float h0 = __uint_as_float(h << 16);
  float h1 = __uint_as_float(h & 0xffff0000u);
  hw = h;
  lw = cvt_pk_bf16(v0 - h0, v1 - h1);
}

// byte address of (row, byteoff) in a row-stride-128B tile image, XOR-swizzled.
#define SWZ(row, byteoff) ((((row) * 128) + (byteoff)) ^ (((row) & 7) << 4))

// sigma: key -> storage col within a 64-block so PV fragment (ks,g) reads keys
// kappa(ks,g,j)=16(ks+2(j>>2))+4g+(j&3) as contiguous cols 32ks+8g+j.
static __device__ __forceinline__ int sigma64(int k) {
  return (k & 3) | (((k >> 5) & 1) << 2) | (((k >> 2) & 3) << 3) | (((k >> 4) & 1) << 5);
}

#define GLOAD16(gp, lp)                                              \
  __builtin_amdgcn_global_load_lds(                                  \
      (const __attribute__((address_space(1))) void*)(gp),           \
      (__attribute__((address_space(3))) void*)(lp), 16, 0, 0)

// ---------------- weight prep (fragment-packed) ----------------
__global__ __launch_bounds__(256) void prep_weights(const float* __restrict__ Wq,
                                                    const float* __restrict__ Wk,
                                                    const float* __restrict__ Wv,
                                                    const float* __restrict__ Wo,
                                                    u16* __restrict__ Wall_h,
                                                    u16* __restrict__ Wall_l,
                                                    u16* __restrict__ WoTp) {
  int i = blockIdx.x * 256 + threadIdx.x;
  if (i < 786432) {
    int which = i / 262144, rem = i - which * 262144;
    int b = rem >> 15, r2 = rem & 32767;
    int c = r2 >> 9, r = r2 & 511;
    const float* W = which == 0 ? Wq : which == 1 ? Wk : Wv;
    float x = W[(b << 15) + r * 64 + c];
    u16 h = f2bf(x);
    size_t off = (size_t)(which * 8 + b) * 32768 +
                 (size_t)((r >> 5) * 4 + (c >> 4)) * 512 +
                 ((((r & 31) >> 3) * 16) + (c & 15)) * 8 + (r & 7);
    Wall_h[off] = h;
    Wall_l[off] = f2bf(x - bf2f(h));
  } else if (i < 786432 + 262144) {
    int rem = i - 786432;
    int c = rem >> 9, r = rem & 511;
    size_t off = (size_t)(c >> 6) * 32768 +
                 (size_t)((r >> 5) * 4 + ((c >> 4) & 3)) * 512 +
                 ((((r & 31) >> 3) * 16) + (c & 15)) * 8 + (r & 7);
    WoTp[off] = f2bf(Wo[r * 512 + c]);
  }
}

// ------------- fused projection GEMM -------------
// which 0: q fp16 [h][n][64] (scale 1/8). which 1: k fp16 -> swizzled 8KB
// tile images. which 2: v bf16 -> swizzled sigma-permuted images.
__global__ __launch_bounds__(256) void proj_gemm(const float* __restrict__ Q,
                                                 const float* __restrict__ Kin,
                                                 const float* __restrict__ Vin,
                                                 const u16* __restrict__ Wall_h,
                                                 const u16* __restrict__ Wall_l,
                                                 u16* __restrict__ qh,
                                                 u16* __restrict__ khg,
                                                 u16* __restrict__ vsg) {
  const int n = 4096, K = 512, N = 64;
  int rb = blockIdx.x;
  int which = blockIdx.y >> 3, b = blockIdx.y & 7;
  int wave = threadIdx.x >> 6, lane = threadIdx.x & 63;
  int lr = lane & 15, lg = lane >> 4;
  int row0 = rb * 64 + wave * 16;

  const float* A = which == 0 ? Q : which == 1 ? Kin : Vin;
  const u16* Bh = Wall_h + (size_t)(which * 8 + b) * 32768 + lane * 8;
  const u16* Bl = Wall_l + (size_t)(which * 8 + b) * 32768 + lane * 8;
  float scale = which == 0 ? 0.125f : 1.0f;

  const float* Arow = A + (size_t)(row0 + lr) * K + lg * 8;

  union U8 { unsigned w[4]; bf16x8 v; };
  f32x4 acc[4] = {};

  float4 a0 = *(const float4*)(Arow);
  float4 a1 = *(const float4*)(Arow + 4);
  bf16x8 bh[4], bl[4];
#pragma unroll
  for (int ct = 0; ct < 4; ++ct) {
    bh[ct] = *(const bf16x8*)(Bh + ct * 512);
    bl[ct] = *(const bf16x8*)(Bl + ct * 512);
  }

#pragma unroll
  for (int ks = 0; ks < 16; ++ks) {
    float4 a0n, a1n;
    bf16x8 bhn[4], bln[4];
    if (ks < 15) {
      a0n = *(const float4*)(Arow + (ks + 1) * 32);
      a1n = *(const float4*)(Arow + (ks + 1) * 32 + 4);
#pragma unroll
      for (int ct = 0; ct < 4; ++ct) {
        bhn[ct] = *(const bf16x8*)(Bh + ((ks + 1) * 4 + ct) * 512);
        bln[ct] = *(const bf16x8*)(Bl + ((ks + 1) * 4 + ct) * 512);
      }
    }
    U8 ah, al;
    split2(a0.x, a0.y, ah.w[0], al.w[0]);
    split2(a0.z, a0.w, ah.w[1], al.w[1]);
    split2(a1.x, a1.y, ah.w[2], al.w[2]);
    split2(a1.z, a1.w, ah.w[3], al.w[3]);
#pragma unroll
    for (int ct = 0; ct < 4; ++ct) {
      acc[ct] = __builtin_amdgcn_mfma_f32_16x16x32_bf16(ah.v, bh[ct], acc[ct], 0, 0, 0);
      acc[ct] = __builtin_amdgcn_mfma_f32_16x16x32_bf16(al.v, bh[ct], acc[ct], 0, 0, 0);
      acc[ct] = __builtin_amdgcn_mfma_f32_16x16x32_bf16(ah.v, bl[ct], acc[ct], 0, 0, 0);
    }
    if (ks < 15) {
      a0 = a0n; a1 = a1n;
#pragma unroll
      for (int ct = 0; ct < 4; ++ct) { bh[ct] = bhn[ct]; bl[ct] = bln[ct]; }
    }
  }

#pragma unroll
  for (int ct = 0; ct < 4; ++ct)
#pragma unroll
    for (int r = 0; r < 4; ++r) {
      float v = acc[ct][r] * scale;
      int row = row0 + lg * 4 + r;
      int col = ct * 16 + lr;
      if (which == 2) {
        size_t byte = ((size_t)b * 64 + (row >> 6)) * 8192 +
                      SWZ(col, 2 * sigma64(row & 63));
        *(u16*)((char*)vsg + byte) = f2bf(v);
      } else if (which == 1) {
        size_t byte = ((size_t)b * 64 + (row >> 6)) * 8192 + SWZ(row & 63, col * 2);
        *(u16*)((char*)khg + byte) = f2h(v);
      } else {
        qh[((size_t)b * n + row) * N + col] = f2h(v);
      }
    }
}

// ---------------- flash attention: 4 waves x 32 q-rows, split-KV x4 ----------------
// qh: [8][4096][64] fp16 (pre-scaled 1/8); khg: fp16 swizzled images;
// vsg: bf16 swizzled sigma-permuted images.
// Opart: [4][8][4096][64] bf16 unnormalized; ml: [4][8][4096] float2 (m, l)
__global__ __launch_bounds__(256, 4) void attn_kernel(const u16* __restrict__ qh,
                                                      const u16* __restrict__ khg,
                                                      const u16* __restrict__ vsg,
                                                      u16* __restrict__ Opart,
                                                      float2* __restrict__ ml) {
  const int n = 4096, d = 64;
  int qb = blockIdx.x, h = blockIdx.y, part = blockIdx.z;
  int wave = threadIdx.x >> 6, lane = threadIdx.x & 63;
  int c = lane & 15, g = lane >> 4;

  __shared__ char SB[32768];  // [KH0 8K][KH1 8K][VS0 8K][VS1 8K]

  int qrow0 = qb * 128 + wave * 32;
  f16x8 qf[2][2];
#pragma unroll
  for (int b2 = 0; b2 < 2; ++b2)
#pragma unroll
    for (int ks = 0; ks < 2; ++ks) {
      size_t qoff = ((size_t)h * n + qrow0 + b2 * 16 + c) * d + ks * 32 + g * 8;
      qf[b2][ks] = *(const f16x8*)(qh + qoff);
    }

  f32x4 accO[2][4] = {};
  float m[2] = {-INFINITY, -INFINITY}, l[2] = {0.f, 0.f};

  const char* khB = (const char*)khg + ((size_t)h * 64 + part * 16) * 8192;
  const char* vsB = (const char*)vsg + ((size_t)h * 64 + part * 16) * 8192;
  int so = wave * 2048;       // wave-uniform LDS slice
  int sg = so + lane * 16;    // per-lane global offset

#define STAGE(tile, buf)                                            \
  do {                                                              \
    const char* kg_ = khB + (size_t)(tile) * 8192 + sg;             \
    const char* vg_ = vsB + (size_t)(tile) * 8192 + sg;             \
    char* kd_ = SB + (buf) * 8192 + so;                             \
    char* vd_ = SB + 16384 + (buf) * 8192 + so;                     \
    GLOAD16(kg_, kd_);                                              \
    GLOAD16(kg_ + 1024, kd_ + 1024);                                \
    GLOAD16(vg_, vd_);                                              \
    GLOAD16(vg_ + 1024, vd_ + 1024);                                \
  } while (0)

  STAGE(0, 0);

  for (int it = 0; it < 16; ++it) {
    int cur = it & 1;
    asm volatile("s_waitcnt vmcnt(0)" ::: "memory");  // my slice of tile it landed
    __builtin_amdgcn_s_barrier();                     // all waves' slices landed
    if (it < 15) STAGE(it + 1, cur ^ 1);  // prefetch hides under QK+softmax+PV

    const char* KHb = SB + cur * 8192;
    const char* VSb = SB + 16384 + cur * 8192;

    union { unsigned w[4]; bf16x8 v; } pa[2][2];
#pragma unroll
    for (int b2 = 0; b2 < 2; ++b2) {
      // S^T = K @ Q^T (fp16): s[ct] reg r = P~[key=ct*16+g*4+r][q=b2*16+c]
      f32x4 s[4] = {};
#pragma unroll
      for (int ct = 0; ct < 4; ++ct) {
        int R = ct * 16 + c;
#pragma unroll
        for (int ks = 0; ks < 2; ++ks) {
          f16x8 kf = *(const f16x8*)(KHb + SWZ(R, ks * 64 + g * 16));
          s[ct] = __builtin_amdgcn_mfma_f32_16x16x32_f16(kf, qf[b2][ks], s[ct], 0, 0, 0);
        }
      }

      // in-register online softmax for q-row (b2*16 + c)
      float mx0 = fmaxf(fmaxf(s[0][0], s[0][1]), fmaxf(s[0][2], s[0][3]));
      float mx1 = fmaxf(fmaxf(s[1][0], s[1][1]), fmaxf(s[1][2], s[1][3]));
      float mx2 = fmaxf(fmaxf(s[2][0], s[2][1]), fmaxf(s[2][2], s[2][3]));
      float mx3 = fmaxf(fmaxf(s[3][0], s[3][1]), fmaxf(s[3][2], s[3][3]));
      float mx = fmaxf(fmaxf(mx0, mx1), fmaxf(mx2, mx3));
      mx = fmaxf(mx, __shfl_xor(mx, 16));
      mx = fmaxf(mx, __shfl_xor(mx, 32));
      bool need = mx > m[b2];
      float mn = need ? mx : m[b2];
      float rs = 0.f;
#pragma unroll
      for (int ct = 0; ct < 4; ++ct) {
        float q0 = __expf(s[ct][0] - mn);
        float q1 = __expf(s[ct][1] - mn);
        float q2 = __expf(s[ct][2] - mn);
        float q3 = __expf(s[ct][3] - mn);
        s[ct][0] = q0; s[ct][1] = q1; s[ct][2] = q2; s[ct][3] = q3;
        rs += (q0 + q1) + (q2 + q3);
      }
      rs += __shfl_xor(rs, 16);
      rs += __shfl_xor(rs, 32);

      if (__any(need)) {  // exact defer-rescale
        float alpha = __expf(m[b2] - mn);
        m[b2] = mn;
        l[b2] = l[b2] * alpha + rs;
#pragma unroll
        for (int r = 0; r < 4; ++r) {
          float ar = __shfl(alpha, g * 4 + r);
#pragma unroll
          for (int dt = 0; dt < 4; ++dt) accO[b2][dt][r] *= ar;
        }
      } else {
        l[b2] += rs;
      }

      // pack P in-lane: PV HW slot (ks; g, j) holds key 16(ks+2(j>>2))+4g+(j&3)
#pragma unroll
      for (int ks = 0; ks < 2; ++ks) {
        pa[b2][ks].w[0] = cvt_pk_bf16(s[ks][0], s[ks][1]);
        pa[b2][ks].w[1] = cvt_pk_bf16(s[ks][2], s[ks][3]);
        pa[b2][ks].w[2] = cvt_pk_bf16(s[ks + 2][0], s[ks + 2][1]);
        pa[b2][ks].w[3] = cvt_pk_bf16(s[ks + 2][2], s[ks + 2][3]);
      }
    }

    // O += P @ V: V fragments shared across both q-blocks (read once)
#pragma unroll
    for (int dt = 0; dt < 4; ++dt) {
      int R = dt * 16 + c;
#pragma unroll
      for (int ks = 0; ks < 2; ++ks) {
        bf16x8 vf = *(const bf16x8*)(VSb + SWZ(R, ks * 64 + g * 16));
        accO[0][dt] = __builtin_amdgcn_mfma_f32_16x16x32_bf16(pa[0][ks].v, vf, accO[0][dt], 0, 0, 0);
        accO[1][dt] = __builtin_amdgcn_mfma_f32_16x16x32_bf16(pa[1][ks].v, vf, accO[1][dt], 0, 0, 0);
      }
    }
    __builtin_amdgcn_s_barrier();  // all waves done reading buf cur
  }
#undef STAGE

  // epilogue: unnormalized O + (m,l)
  u16* Ob = Opart + (((size_t)part * 8 + h) * n) * d;
  float2* mlp = ml + ((size_t)part * 8 + h) * n;
#pragma unroll
  for (int b2 = 0; b2 < 2; ++b2) {
#pragma unroll
    for (int r = 0; r < 4; ++r) {
      int row = qrow0 + b2 * 16 + g * 4 + r;
#pragma unroll
      for (int dt = 0; dt < 4; ++dt)
        Ob[(size_t)row * d + dt * 16 + c] = f2bf(accO[b2][dt][r]);
    }
    if (g == 0) mlp[qrow0 + b2 * 16 + c] = make_float2(m[b2], l[b2]);
  }
}

// ---------------- combine the four KV parts ----------------
__global__ __launch_bounds__(256) void attn_combine(const u16* __restrict__ Opart,
                                                    const float2* __restrict__ ml,
                                                    u16* __restrict__ att) {
  int tid = blockIdx.x * 256 + threadIdx.x;  // 4096*8*8 threads
  int chunk = tid & 7;
  int h = (tid >> 3) & 7;
  int row = tid >> 6;
  float2 mls[4];
  float mstar = -INFINITY;
#pragma unroll
  for (int p = 0; p < 4; ++p) {
    mls[p] = ml[((size_t)p * 8 + h) * 4096 + row];
    mstar = fmaxf(mstar, mls[p].x);
  }
  float w[4], denom = 0.f;
#pragma unroll
  for (int p = 0; p < 4; ++p) {
    w[p] = __expf(mls[p].x - mstar);
    denom += mls[p].y * w[p];
  }
  float inv = 1.f / denom;
  float res[8] = {};
#pragma unroll
  for (int p = 0; p < 4; ++p) {
    bf16x8 o = *(const bf16x8*)(Opart + (((size_t)p * 8 + h) * 4096 + row) * 64 + chunk * 8);
    float wp = w[p] * inv;
#pragma unroll
    for (int j = 0; j < 8; ++j) res[j] += bf2f((u16)o[j]) * wp;
  }
  bf16x8 rv;
#pragma unroll
  for (int j = 0; j < 8; ++j) rv[j] = (short)f2bf(res[j]);
  *(bf16x8*)(att + (size_t)row * 512 + h * 64 + chunk * 8) = rv;
}

// ------- final projection: out = att @ Wo (fp32 out), fragment-packed B -------
__global__ __launch_bounds__(256) void final_gemm(const u16* __restrict__ A,
                                                  const u16* __restrict__ BTp,
                                                  float* __restrict__ out,
                                                  int M, int K, int N) {
  int rb = blockIdx.x, cb = blockIdx.y;
  int wave = threadIdx.x >> 6, lane = threadIdx.x & 63;
  int lr = lane & 15, lg = lane >> 4;
  int row0 = rb * 64 + wave * 16;

  const u16* Arow = A + (size_t)(row0 + lr) * K + lg * 8;
  const u16* Bp = BTp + (size_t)cb * 32768 + lane * 8;

  f32x4 acc[4] = {};
  bf16x8 a = *(const bf16x8*)(Arow);
  bf16x8 bfr[4];
#pragma unroll
  for (int ct = 0; ct < 4; ++ct) bfr[ct] = *(const bf16x8*)(Bp + ct * 512);

#pragma unroll
  for (int ks = 0; ks < 16; ++ks) {
    bf16x8 an, bfn[4];
    if (ks < 15) {
      an = *(const bf16x8*)(Arow + (ks + 1) * 32);
#pragma unroll
      for (int ct = 0; ct < 4; ++ct)
        bfn[ct] = *(const bf16x8*)(Bp + ((ks + 1) * 4 + ct) * 512);
    }
#pragma unroll
    for (int ct = 0; ct < 4; ++ct)
      acc[ct] = __builtin_amdgcn_mfma_f32_16x16x32_bf16(a, bfr[ct], acc[ct], 0, 0, 0);
    if (ks < 15) {
      a = an;
#pragma unroll
      for (int ct = 0; ct < 4; ++ct) bfr[ct] = bfn[ct];
    }
  }
#pragma unroll
  for (int ct = 0; ct < 4; ++ct)
#pragma unroll
    for (int r = 0; r < 4; ++r)
      out[(size_t)(row0 + lg * 4 + r) * N + cb * 64 + ct * 16 + lr] = acc[ct][r];
}

// ---------------- launch ----------------
extern "C" void kernel_launch(void* const* d_in, const int* in_sizes, int n_in,
                              void* d_out, int out_size, void* d_ws, size_t ws_size,
                              hipStream_t stream) {
  const float* Q = (const float*)d_in[0];
  const float* K = (const float*)d_in[1];
  const float* V = (const float*)d_in[2];
  const float* Wq = (const float*)d_in[3];
  const float* Wk = (const float*)d_in[4];
  const float* Wv = (const float*)d_in[5];
  const float* Wo = (const float*)d_in[6];
  float* out = (float*)d_out;

  const int n = 4096, dim = 512;
  const size_t KB = 1 << 10, MB = 1 << 20;
  char* ws = (char*)d_ws;
  u16* qh     = (u16*)(ws + 0 * MB);   // 4 MB, fp16
  u16* khg    = (u16*)(ws + 4 * MB);   // 4 MB, fp16 swizzled images
  u16* vsg    = (u16*)(ws + 8 * MB);   // 4 MB, bf16 swizzled sigma-permuted
  u16* Opart  = (u16*)(ws + 12 * MB);  // 16 MB (4 parts) -> ends 28 MB
  u16* Wall_h = (u16*)(ws + 12 * MB);             // 1.5 MB, inside Opart (dead by attn)
  u16* Wall_l = (u16*)(ws + 12 * MB + 1536 * KB); // 1.5 MB, inside Opart
  float2* ml  = (float2*)(ws + 28 * MB);          // 1 MB
  u16* WoTp   = (u16*)(ws + 29 * MB);             // 512 KB -> peak 29.5 MB
  u16* att    = khg;  // khg dead after attn; combine writes att here

  prep_weights<<<4096, 256, 0, stream>>>(Wq, Wk, Wv, Wo, Wall_h, Wall_l, WoTp);

  proj_gemm<<<dim3(n / 64, 24), 256, 0, stream>>>(Q, K, V, Wall_h, Wall_l,
                                                  qh, khg, vsg);

  attn_kernel<<<dim3(32, 8, 4), 256, 0, stream>>>(qh, khg, vsg, Opart, ml);
  attn_combine<<<(n * 8 * 8) / 256, 256, 0, stream>>>(Opart, ml, att);

  final_gemm<<<dim3(n / 64, dim / 64), 256, 0, stream>>>(att, WoTp, out, n, dim, dim);
}

// Round 9
// 124.216 us; speedup vs baseline: 3.3580x; 1.0622x over previous
//
#include <hip/hip_runtime.h>

// MultiHeadAttentionLayer: n=4096, dim=512, h=8, d=64, fp32 in/out.
// R9: attn -> exp2 domain (log2e folded into q scale, bare v_exp_f32), shared
// K-fragments across the two q-subtiles, interleaved b2 softmax (overlapping
// shfl chains), max3 trees, setprio around MFMA clusters, XCD-locality block
// swizzle (one head per XCD -> KV L2-hot). proj: v is single bf16 MFMA.

typedef __attribute__((ext_vector_type(8))) short bf16x8;
typedef __attribute__((ext_vector_type(8))) _Float16 f16x8;
typedef __attribute__((ext_vector_type(4))) float f32x4;
typedef unsigned short u16;

static __device__ __forceinline__ u16 f2bf(float f) {
  union { float f; unsigned u; } v; v.f = f;
  unsigned r = v.u + 0x7fffu + ((v.u >> 16) & 1u);
  return (u16)(r >> 16);
}
static __device__ __forceinline__ float bf2f(u16 h) {
  union { unsigned u; float f; } v; v.u = ((unsigned)h) << 16; return v.f;
}
static __device__ __forceinline__ u16 f2h(float f) {
  union { _Float16 h; u16 u; } v; v.h = (_Float16)f; return v.u;
}
static __device__ __forceinline__ unsigned cvt_pk_bf16(float lo, float hi) {
  unsigned r;
  asm("v_cvt_pk_bf16_f32 %0, %1, %2" : "=v"(r) : "v"(lo), "v"(hi));
  return r;
}
static __device__ __forceinline__ float exp2a(float x) {  // 2^x, one v_exp_f32
  float r;
  asm("v_exp_f32 %0, %1" : "=v"(r) : "v"(x));
  return r;
}
static __device__ __forceinline__ void split2(float v0, float v1,
                                              unsigned& hw, unsigned& lw) {
  unsigned h = cvt_pk_bf16(v0, v1);
  float h0 = __uint_as_float(h << 16);
  float h1 = __uint_as_float(h & 0xffff0000u);
  hw = h;
  lw = cvt_pk_bf16(v0 - h0, v1 - h1);
}

#define MAX3(a, b, c) fmaxf(fmaxf(a, b), c)

// byte address of (row, byteoff) in a row-stride-128B tile image, XOR-swizzled.
#define SWZ(row, byteoff) ((((row) * 128) + (byteoff)) ^ (((row) & 7) << 4))

// sigma: key -> storage col within a 64-block so PV fragment (ks,g) reads keys
// kappa(ks,g,j)=16(ks+2(j>>2))+4g+(j&3) as contiguous cols 32ks+8g+j.
static __device__ __forceinline__ int sigma64(int k) {
  return (k & 3) | (((k >> 5) & 1) << 2) | (((k >> 2) & 3) << 3) | (((k >> 4) & 1) << 5);
}

#define GLOAD16(gp, lp)                                              \
  __builtin_amdgcn_global_load_lds(                                  \
      (const __attribute__((address_space(1))) void*)(gp),           \
      (__attribute__((address_space(3))) void*)(lp), 16, 0, 0)

// ---------------- weight prep (fragment-packed) ----------------
__global__ __launch_bounds__(256) void prep_weights(const float* __restrict__ Wq,
                                                    const float* __restrict__ Wk,
                                                    const float* __restrict__ Wv,
                                                    const float* __restrict__ Wo,
                                                    u16* __restrict__ Wall_h,
                                                    u16* __restrict__ Wall_l,
                                                    u16* __restrict__ WoTp) {
  int i = blockIdx.x * 256 + threadIdx.x;
  if (i < 786432) {
    int which = i / 262144, rem = i - which * 262144;
    int b = rem >> 15, r2 = rem & 32767;
    int c = r2 >> 9, r = r2 & 511;
    const float* W = which == 0 ? Wq : which == 1 ? Wk : Wv;
    float x = W[(b << 15) + r * 64 + c];
    u16 h = f2bf(x);
    size_t off = (size_t)(which * 8 + b) * 32768 +
                 (size_t)((r >> 5) * 4 + (c >> 4)) * 512 +
                 ((((r & 31) >> 3) * 16) + (c & 15)) * 8 + (r & 7);
    Wall_h[off] = h;
    Wall_l[off] = f2bf(x - bf2f(h));
  } else if (i < 786432 + 262144) {
    int rem = i - 786432;
    int c = rem >> 9, r = rem & 511;
    size_t off = (size_t)(c >> 6) * 32768 +
                 (size_t)((r >> 5) * 4 + ((c >> 4) & 3)) * 512 +
                 ((((r & 31) >> 3) * 16) + (c & 15)) * 8 + (r & 7);
    WoTp[off] = f2bf(Wo[r * 512 + c]);
  }
}

// ------------- fused projection GEMM -------------
// which 0: q fp16 [h][n][64] (scale log2e/8). which 1: k fp16 -> swizzled 8KB
// tile images. which 2: v bf16 -> swizzled sigma-permuted images (single-term).
__global__ __launch_bounds__(256) void proj_gemm(const float* __restrict__ Q,
                                                 const float* __restrict__ Kin,
                                                 const float* __restrict__ Vin,
                                                 const u16* __restrict__ Wall_h,
                                                 const u16* __restrict__ Wall_l,
                                                 u16* __restrict__ qh,
                                                 u16* __restrict__ khg,
                                                 u16* __restrict__ vsg) {
  const int n = 4096, K = 512, N = 64;
  int rb = blockIdx.x;
  int which = blockIdx.y >> 3, b = blockIdx.y & 7;
  int wave = threadIdx.x >> 6, lane = threadIdx.x & 63;
  int lr = lane & 15, lg = lane >> 4;
  int row0 = rb * 64 + wave * 16;

  const float* A = which == 0 ? Q : which == 1 ? Kin : Vin;
  const u16* Bh = Wall_h + (size_t)(which * 8 + b) * 32768 + lane * 8;
  const u16* Bl = Wall_l + (size_t)(which * 8 + b) * 32768 + lane * 8;

  const float* Arow = A + (size_t)(row0 + lr) * K + lg * 8;

  union U8 { unsigned w[4]; bf16x8 v; };
  f32x4 acc[4] = {};

  float4 a0 = *(const float4*)(Arow);
  float4 a1 = *(const float4*)(Arow + 4);
  bf16x8 bh[4], bl[4];
#pragma unroll
  for (int ct = 0; ct < 4; ++ct) bh[ct] = *(const bf16x8*)(Bh + ct * 512);
  if (which != 2) {
#pragma unroll
    for (int ct = 0; ct < 4; ++ct) bl[ct] = *(const bf16x8*)(Bl + ct * 512);
  }

#pragma unroll
  for (int ks = 0; ks < 16; ++ks) {
    float4 a0n, a1n;
    bf16x8 bhn[4], bln[4];
    if (ks < 15) {
      a0n = *(const float4*)(Arow + (ks + 1) * 32);
      a1n = *(const float4*)(Arow + (ks + 1) * 32 + 4);
#pragma unroll
      for (int ct = 0; ct < 4; ++ct)
        bhn[ct] = *(const bf16x8*)(Bh + ((ks + 1) * 4 + ct) * 512);
      if (which != 2) {
#pragma unroll
        for (int ct = 0; ct < 4; ++ct)
          bln[ct] = *(const bf16x8*)(Bl + ((ks + 1) * 4 + ct) * 512);
      }
    }
    U8 ah, al;
    split2(a0.x, a0.y, ah.w[0], al.w[0]);
    split2(a0.z, a0.w, ah.w[1], al.w[1]);
    split2(a1.x, a1.y, ah.w[2], al.w[2]);
    split2(a1.z, a1.w, ah.w[3], al.w[3]);
#pragma unroll
    for (int ct = 0; ct < 4; ++ct)
      acc[ct] = __builtin_amdgcn_mfma_f32_16x16x32_bf16(ah.v, bh[ct], acc[ct], 0, 0, 0);
    if (which != 2) {
#pragma unroll
      for (int ct = 0; ct < 4; ++ct) {
        acc[ct] = __builtin_amdgcn_mfma_f32_16x16x32_bf16(al.v, bh[ct], acc[ct], 0, 0, 0);
        acc[ct] = __builtin_amdgcn_mfma_f32_16x16x32_bf16(ah.v, bl[ct], acc[ct], 0, 0, 0);
      }
    }
    if (ks < 15) {
      a0 = a0n; a1 = a1n;
#pragma unroll
      for (int ct = 0; ct < 4; ++ct) bh[ct] = bhn[ct];
      if (which != 2) {
#pragma unroll
        for (int ct = 0; ct < 4; ++ct) bl[ct] = bln[ct];
      }
    }
  }

  const float QSCALE = 0.125f * 1.44269504f;  // 1/sqrt(64) * log2(e)
#pragma unroll
  for (int ct = 0; ct < 4; ++ct)
#pragma unroll
    for (int r = 0; r < 4; ++r) {
      float v = acc[ct][r];
      int row = row0 + lg * 4 + r;
      int col = ct * 16 + lr;
      if (which == 2) {
        size_t byte = ((size_t)b * 64 + (row >> 6)) * 8192 +
                      SWZ(col, 2 * sigma64(row & 63));
        *(u16*)((char*)vsg + byte) = f2bf(v);
      } else if (which == 1) {
        size_t byte = ((size_t)b * 64 + (row >> 6)) * 8192 + SWZ(row & 63, col * 2);
        *(u16*)((char*)khg + byte) = f2h(v);
      } else {
        qh[((size_t)b * n + row) * N + col] = f2h(v * QSCALE);
      }
    }
}

// ---------------- flash attention: 4 waves x 32 q-rows, split-KV x4 ----------------
// qh fp16 (pre-scaled log2e/8); khg fp16 images; vsg bf16 sigma images.
// m is tracked in log2 units (scores already scaled by log2e).
// Block swizzle: all 128 blocks of head h land on XCD h (bid%8==h).
__global__ __launch_bounds__(256, 4) void attn_kernel(const u16* __restrict__ qh,
                                                      const u16* __restrict__ khg,
                                                      const u16* __restrict__ vsg,
                                                      u16* __restrict__ Opart,
                                                      float2* __restrict__ ml) {
  const int n = 4096, d = 64;
  int bid = blockIdx.x;
  int j = bid & 7, w = bid >> 3;
  int grp = j * 4 + (w >> 5);  // = h*4 + part; all blocks of grp share bid%8
  int qb = w & 31;
  int h = grp >> 2, part = grp & 3;
  int wave = threadIdx.x >> 6, lane = threadIdx.x & 63;
  int c = lane & 15, g = lane >> 4;

  __shared__ char SB[32768];  // [KH0 8K][KH1 8K][VS0 8K][VS1 8K]

  int qrow0 = qb * 128 + wave * 32;
  f16x8 qf[2][2];
#pragma unroll
  for (int b2 = 0; b2 < 2; ++b2)
#pragma unroll
    for (int ks = 0; ks < 2; ++ks) {
      size_t qoff = ((size_t)h * n + qrow0 + b2 * 16 + c) * d + ks * 32 + g * 8;
      qf[b2][ks] = *(const f16x8*)(qh + qoff);
    }

  f32x4 accO[2][4] = {};
  float m[2] = {-INFINITY, -INFINITY}, l[2] = {0.f, 0.f};

  const char* khB = (const char*)khg + ((size_t)h * 64 + part * 16) * 8192;
  const char* vsB = (const char*)vsg + ((size_t)h * 64 + part * 16) * 8192;
  int so = wave * 2048;
  int sg = so + lane * 16;

#define STAGE(tile, buf)                                            \
  do {                                                              \
    const char* kg_ = khB + (size_t)(tile) * 8192 + sg;             \
    const char* vg_ = vsB + (size_t)(tile) * 8192 + sg;             \
    char* kd_ = SB + (buf) * 8192 + so;                             \
    char* vd_ = SB + 16384 + (buf) * 8192 + so;                     \
    GLOAD16(kg_, kd_);                                              \
    GLOAD16(kg_ + 1024, kd_ + 1024);                                \
    GLOAD16(vg_, vd_);                                              \
    GLOAD16(vg_ + 1024, vd_ + 1024);                                \
  } while (0)

  STAGE(0, 0);

  for (int it = 0; it < 16; ++it) {
    int cur = it & 1;
    asm volatile("s_waitcnt vmcnt(0)" ::: "memory");
    __builtin_amdgcn_s_barrier();
    if (it < 15) STAGE(it + 1, cur ^ 1);

    const char* KHb = SB + cur * 8192;
    const char* VSb = SB + 16384 + cur * 8192;

    // QK^T for both q-subtiles, K fragment read once and shared.
    f32x4 s[2][4] = {};
    __builtin_amdgcn_s_setprio(1);
#pragma unroll
    for (int ct = 0; ct < 4; ++ct) {
      int R = ct * 16 + c;
#pragma unroll
      for (int ks = 0; ks < 2; ++ks) {
        f16x8 kf = *(const f16x8*)(KHb + SWZ(R, ks * 64 + g * 16));
        s[0][ct] = __builtin_amdgcn_mfma_f32_16x16x32_f16(kf, qf[0][ks], s[0][ct], 0, 0, 0);
        s[1][ct] = __builtin_amdgcn_mfma_f32_16x16x32_f16(kf, qf[1][ks], s[1][ct], 0, 0, 0);
      }
    }
    __builtin_amdgcn_s_setprio(0);

    // interleaved online softmax (log2 domain) for both q-subtiles
    float mxv[2], mn[2], rs[2];
    bool need[2];
#pragma unroll
    for (int b2 = 0; b2 < 2; ++b2) {
      float t0 = MAX3(s[b2][0][0], s[b2][0][1], s[b2][0][2]);
      float t1 = MAX3(s[b2][0][3], s[b2][1][0], s[b2][1][1]);
      float t2 = MAX3(s[b2][1][2], s[b2][1][3], s[b2][2][0]);
      float t3 = MAX3(s[b2][2][1], s[b2][2][2], s[b2][2][3]);
      float t4 = MAX3(s[b2][3][0], s[b2][3][1], s[b2][3][2]);
      mxv[b2] = fmaxf(MAX3(t0, t1, t2), MAX3(t3, t4, s[b2][3][3]));
    }
#pragma unroll
    for (int b2 = 0; b2 < 2; ++b2) mxv[b2] = fmaxf(mxv[b2], __shfl_xor(mxv[b2], 16));
#pragma unroll
    for (int b2 = 0; b2 < 2; ++b2) mxv[b2] = fmaxf(mxv[b2], __shfl_xor(mxv[b2], 32));
#pragma unroll
    for (int b2 = 0; b2 < 2; ++b2) {
      need[b2] = mxv[b2] > m[b2];
      mn[b2] = need[b2] ? mxv[b2] : m[b2];
      float r0 = 0.f, r1 = 0.f;
#pragma unroll
      for (int ct = 0; ct < 4; ++ct) {
        float q0 = exp2a(s[b2][ct][0] - mn[b2]);
        float q1 = exp2a(s[b2][ct][1] - mn[b2]);
        float q2 = exp2a(s[b2][ct][2] - mn[b2]);
        float q3 = exp2a(s[b2][ct][3] - mn[b2]);
        s[b2][ct][0] = q0; s[b2][ct][1] = q1; s[b2][ct][2] = q2; s[b2][ct][3] = q3;
        r0 += q0 + q1; r1 += q2 + q3;
      }
      rs[b2] = r0 + r1;
    }
#pragma unroll
    for (int b2 = 0; b2 < 2; ++b2) rs[b2] += __shfl_xor(rs[b2], 16);
#pragma unroll
    for (int b2 = 0; b2 < 2; ++b2) rs[b2] += __shfl_xor(rs[b2], 32);
#pragma unroll
    for (int b2 = 0; b2 < 2; ++b2) {
      if (__any(need[b2])) {
        float alpha = exp2a(m[b2] - mn[b2]);
        m[b2] = mn[b2];
        l[b2] = l[b2] * alpha + rs[b2];
#pragma unroll
        for (int r = 0; r < 4; ++r) {
          float ar = __shfl(alpha, g * 4 + r);
#pragma unroll
          for (int dt = 0; dt < 4; ++dt) accO[b2][dt][r] *= ar;
        }
      } else {
        l[b2] += rs[b2];
      }
    }

    // pack P in-lane: PV HW slot (ks; g, j) holds key 16(ks+2(j>>2))+4g+(j&3)
    union { unsigned w[4]; bf16x8 v; } pa[2][2];
#pragma unroll
    for (int b2 = 0; b2 < 2; ++b2)
#pragma unroll
      for (int ks = 0; ks < 2; ++ks) {
        pa[b2][ks].w[0] = cvt_pk_bf16(s[b2][ks][0], s[b2][ks][1]);
        pa[b2][ks].w[1] = cvt_pk_bf16(s[b2][ks][2], s[b2][ks][3]);
        pa[b2][ks].w[2] = cvt_pk_bf16(s[b2][ks + 2][0], s[b2][ks + 2][1]);
        pa[b2][ks].w[3] = cvt_pk_bf16(s[b2][ks + 2][2], s[b2][ks + 2][3]);
      }

    // O += P @ V: V fragments shared across both q-subtiles
    __builtin_amdgcn_s_setprio(1);
#pragma unroll
    for (int dt = 0; dt < 4; ++dt) {
      int R = dt * 16 + c;
#pragma unroll
      for (int ks = 0; ks < 2; ++ks) {
        bf16x8 vf = *(const bf16x8*)(VSb + SWZ(R, ks * 64 + g * 16));
        accO[0][dt] = __builtin_amdgcn_mfma_f32_16x16x32_bf16(pa[0][ks].v, vf, accO[0][dt], 0, 0, 0);
        accO[1][dt] = __builtin_amdgcn_mfma_f32_16x16x32_bf16(pa[1][ks].v, vf, accO[1][dt], 0, 0, 0);
      }
    }
    __builtin_amdgcn_s_setprio(0);
    __builtin_amdgcn_s_barrier();
  }
#undef STAGE

  // epilogue: unnormalized O + (m,l); m in log2 units
  u16* Ob = Opart + (((size_t)part * 8 + h) * n) * d;
  float2* mlp = ml + ((size_t)part * 8 + h) * n;
#pragma unroll
  for (int b2 = 0; b2 < 2; ++b2) {
#pragma unroll
    for (int r = 0; r < 4; ++r) {
      int row = qrow0 + b2 * 16 + g * 4 + r;
#pragma unroll
      for (int dt = 0; dt < 4; ++dt)
        Ob[(size_t)row * d + dt * 16 + c] = f2bf(accO[b2][dt][r]);
    }
    if (g == 0) mlp[qrow0 + b2 * 16 + c] = make_float2(m[b2], l[b2]);
  }
}

// ---------------- combine the four KV parts (m in log2 units) ----------------
__global__ __launch_bounds__(256) void attn_combine(const u16* __restrict__ Opart,
                                                    const float2* __restrict__ ml,
                                                    u16* __restrict__ att) {
  int tid = blockIdx.x * 256 + threadIdx.x;
  int chunk = tid & 7;
  int h = (tid >> 3) & 7;
  int row = tid >> 6;
  float2 mls[4];
  float mstar = -INFINITY;
#pragma unroll
  for (int p = 0; p < 4; ++p) {
    mls[p] = ml[((size_t)p * 8 + h) * 4096 + row];
    mstar = fmaxf(mstar, mls[p].x);
  }
  float w[4], denom = 0.f;
#pragma unroll
  for (int p = 0; p < 4; ++p) {
    w[p] = exp2a(mls[p].x - mstar);
    denom += mls[p].y * w[p];
  }
  float inv = 1.f / denom;
  float res[8] = {};
#pragma unroll
  for (int p = 0; p < 4; ++p) {
    bf16x8 o = *(const bf16x8*)(Opart + (((size_t)p * 8 + h) * 4096 + row) * 64 + chunk * 8);
    float wp = w[p] * inv;
#pragma unroll
    for (int j = 0; j < 8; ++j) res[j] += bf2f((u16)o[j]) * wp;
  }
  bf16x8 rv;
#pragma unroll
  for (int j = 0; j < 8; ++j) rv[j] = (short)f2bf(res[j]);
  *(bf16x8*)(att + (size_t)row * 512 + h * 64 + chunk * 8) = rv;
}

// ------- final projection: out = att @ Wo (fp32 out), fragment-packed B -------
__global__ __launch_bounds__(256) void final_gemm(const u16* __restrict__ A,
                                                  const u16* __restrict__ BTp,
                                                  float* __restrict__ out,
                                                  int M, int K, int N) {
  int rb = blockIdx.x, cb = blockIdx.y;
  int wave = threadIdx.x >> 6, lane = threadIdx.x & 63;
  int lr = lane & 15, lg = lane >> 4;
  int row0 = rb * 64 + wave * 16;

  const u16* Arow = A + (size_t)(row0 + lr) * K + lg * 8;
  const u16* Bp = BTp + (size_t)cb * 32768 + lane * 8;

  f32x4 acc[4] = {};
  bf16x8 a = *(const bf16x8*)(Arow);
  bf16x8 bfr[4];
#pragma unroll
  for (int ct = 0; ct < 4; ++ct) bfr[ct] = *(const bf16x8*)(Bp + ct * 512);

#pragma unroll
  for (int ks = 0; ks < 16; ++ks) {
    bf16x8 an, bfn[4];
    if (ks < 15) {
      an = *(const bf16x8*)(Arow + (ks + 1) * 32);
#pragma unroll
      for (int ct = 0; ct < 4; ++ct)
        bfn[ct] = *(const bf16x8*)(Bp + ((ks + 1) * 4 + ct) * 512);
    }
#pragma unroll
    for (int ct = 0; ct < 4; ++ct)
      acc[ct] = __builtin_amdgcn_mfma_f32_16x16x32_bf16(a, bfr[ct], acc[ct], 0, 0, 0);
    if (ks < 15) {
      a = an;
#pragma unroll
      for (int ct = 0; ct < 4; ++ct) bfr[ct] = bfn[ct];
    }
  }
#pragma unroll
  for (int ct = 0; ct < 4; ++ct)
#pragma unroll
    for (int r = 0; r < 4; ++r)
      out[(size_t)(row0 + lg * 4 + r) * N + cb * 64 + ct * 16 + lr] = acc[ct][r];
}

// ---------------- launch ----------------
extern "C" void kernel_launch(void* const* d_in, const int* in_sizes, int n_in,
                              void* d_out, int out_size, void* d_ws, size_t ws_size,
                              hipStream_t stream) {
  const float* Q = (const float*)d_in[0];
  const float* K = (const float*)d_in[1];
  const float* V = (const float*)d_in[2];
  const float* Wq = (const float*)d_in[3];
  const float* Wk = (const float*)d_in[4];
  const float* Wv = (const float*)d_in[5];
  const float* Wo = (const float*)d_in[6];
  float* out = (float*)d_out;

  const int n = 4096, dim = 512;
  const size_t KB = 1 << 10, MB = 1 << 20;
  char* ws = (char*)d_ws;
  u16* qh     = (u16*)(ws + 0 * MB);   // 4 MB, fp16 (pre-scaled log2e/8)
  u16* khg    = (u16*)(ws + 4 * MB);   // 4 MB, fp16 swizzled images
  u16* vsg    = (u16*)(ws + 8 * MB);   // 4 MB, bf16 swizzled sigma-permuted
  u16* Opart  = (u16*)(ws + 12 * MB);  // 16 MB (4 parts) -> ends 28 MB
  u16* Wall_h = (u16*)(ws + 12 * MB);             // 1.5 MB, inside Opart (dead by attn)
  u16* Wall_l = (u16*)(ws + 12 * MB + 1536 * KB); // 1.5 MB, inside Opart
  float2* ml  = (float2*)(ws + 28 * MB);          // 1 MB
  u16* WoTp   = (u16*)(ws + 29 * MB);             // 512 KB -> peak 29.5 MB
  u16* att    = khg;  // khg dead after attn; combine writes att here

  prep_weights<<<4096, 256, 0, stream>>>(Wq, Wk, Wv, Wo, Wall_h, Wall_l, WoTp);

  proj_gemm<<<dim3(n / 64, 24), 256, 0, stream>>>(Q, K, V, Wall_h, Wall_l,
                                                  qh, khg, vsg);

  attn_kernel<<<1024, 256, 0, stream>>>(qh, khg, vsg, Opart, ml);
  attn_combine<<<(n * 8 * 8) / 256, 256, 0, stream>>>(Opart, ml, att);

  final_gemm<<<dim3(n / 64, dim / 64), 256, 0, stream>>>(att, WoTp, out, n, dim, dim);
}